// Round 18
// baseline (2442.228 us; speedup 1.0000x reference)
//
#include <hip/hip_runtime.h>
#include <hip/hip_bf16.h>
#include <stdint.h>

#define B_ 2
#define L_ 2048
#define D_ 768
#define H_ 12
#define F_ 3072
#define NL_ 12
#define K_ 128
#define G_ 16
#define HD_ 64
#define CPG_ 48
#define M_TOK (B_*L_)
#define SCALE_ 0.125f

typedef __hip_bfloat16 bf16;
typedef __bf16 bf16x8 __attribute__((ext_vector_type(8)));
typedef float f32x4 __attribute__((ext_vector_type(4)));

__device__ __forceinline__ void gload16(const void* g, void* l) {
  __builtin_amdgcn_global_load_lds((const __attribute__((address_space(1))) void*)g,
                                   (__attribute__((address_space(3))) void*)l, 16, 0, 0);
}

// ---------------------------------------------------------------- conv weight pre-transpose
__global__ __launch_bounds__(256) void convw_kernel(const float* __restrict__ w,
                                                    bf16* __restrict__ wT2) {
  int idx = blockIdx.x * 256 + threadIdx.x;
  int ci = idx & 63;
  int row = idx >> 6;
  int d = row % 48;
  int t2 = row / 48;
  int kk = t2 & 127;
  int g = t2 >> 7;
  float v = (ci < 48) ? w[(((size_t)(g * 48 + d) * 48) + ci) * 128 + kk] : 0.f;
  wT2[idx] = __float2bfloat16(v);
}

// ---------------------------------------------------------------- conv via MFMA (dbuf weights)
__global__ __launch_bounds__(256) void conv_mfma(const float* __restrict__ x,
                                                 const bf16* __restrict__ wT2,
                                                 const float* __restrict__ bias,
                                                 float* __restrict__ out) {
  int flat = blockIdx.x;
  int wgid = (flat & 7) * 64 + (flat >> 3);
  const int g = wgid >> 5;
  int rem = wgid & 31;
  const int l0 = (rem & 15) * 128;
  const int b = rem >> 4;

  const int tid = threadIdx.x, w = tid >> 6, lane = tid & 63;
  const int c15 = lane & 15, g4 = lane >> 4;
  __shared__ __align__(16) bf16 win[256 * 64];
  __shared__ __align__(16) bf16 Wl[2][2 * 48 * 64];

  {
    int lg = l0 - 64 + tid;
    char* dst = (char*)win + tid * 128;
    int swr = (tid & 7) << 4;
    uint4 z4 = {0u, 0u, 0u, 0u};
    if ((unsigned)lg < 2048u) {
      const float* srow = x + ((size_t)(b * 2048 + lg) * 768 + g * 48);
#pragma unroll
      for (int c = 0; c < 6; ++c) {
        float4 v0 = *(const float4*)(srow + c * 8);
        float4 v1 = *(const float4*)(srow + c * 8 + 4);
        union { bf16 h[8]; uint4 u; } uu;
        uu.h[0] = __float2bfloat16(v0.x); uu.h[1] = __float2bfloat16(v0.y);
        uu.h[2] = __float2bfloat16(v0.z); uu.h[3] = __float2bfloat16(v0.w);
        uu.h[4] = __float2bfloat16(v1.x); uu.h[5] = __float2bfloat16(v1.y);
        uu.h[6] = __float2bfloat16(v1.z); uu.h[7] = __float2bfloat16(v1.w);
        *(uint4*)(dst + ((c * 16) ^ swr)) = uu.u;
      }
    } else {
#pragma unroll
      for (int c = 0; c < 6; ++c) *(uint4*)(dst + ((c * 16) ^ swr)) = z4;
    }
    *(uint4*)(dst + (96 ^ swr)) = z4;
    *(uint4*)(dst + (112 ^ swr)) = z4;
  }

  const char* wbase = (const char*)wT2 + (size_t)g * 128 * 48 * 128;
  const int coff = w * 3072;
#define STAGEW(kp, bufi)                                                                   \
  {                                                                                        \
    _Pragma("unroll")                                                                      \
    for (int i = 0; i < 3; ++i) {                                                          \
      int c = coff + i * 1024 + (lane << 4);                                               \
      int row96 = c >> 7;                                                                  \
      int s = row96 / 48;                                                                  \
      int d = row96 - s * 48;                                                              \
      int cb2 = c & 127;                                                                   \
      gload16(wbase + ((size_t)((2 * (kp) + s) * 48 + d)) * 128 + (cb2 ^ ((d & 7) << 4)),  \
              (char*)Wl[bufi] + coff + i * 1024);                                          \
    }                                                                                      \
  }

  f32x4 acc[2][3];
  const f32x4 vzero = {0.f, 0.f, 0.f, 0.f};
#pragma unroll
  for (int i = 0; i < 2; ++i)
#pragma unroll
    for (int j = 0; j < 3; ++j) acc[i][j] = vzero;

  STAGEW(0, 0);
  __syncthreads();

  for (int kp = 0; kp < 64; ++kp) {
    int cur = kp & 1;
    if (kp + 1 < 64) STAGEW(kp + 1, cur ^ 1);
    const char* Wc = (const char*)Wl[cur];
#pragma unroll
    for (int s = 0; s < 2; ++s) {
      int kk = 2 * kp + s;
#pragma unroll
      for (int cb = 0; cb < 2; ++cb) {
        int a0r = w * 16 + c15 + kk;
        int a1r = 64 + a0r;
        bf16x8 a0 = *(const bf16x8*)((const char*)win + a0r * 128 + ((cb * 64 + g4 * 16) ^ ((a0r & 7) << 4)));
        bf16x8 a1 = *(const bf16x8*)((const char*)win + a1r * 128 + ((cb * 64 + g4 * 16) ^ ((a1r & 7) << 4)));
#pragma unroll
        for (int ct = 0; ct < 3; ++ct) {
          int d = ct * 16 + c15;
          bf16x8 bfrag = *(const bf16x8*)(Wc + s * 6144 + d * 128 +
                                          ((cb * 64 + g4 * 16) ^ ((d & 7) << 4)));
          acc[0][ct] = __builtin_amdgcn_mfma_f32_16x16x32_bf16(a0, bfrag, acc[0][ct], 0, 0, 0);
          acc[1][ct] = __builtin_amdgcn_mfma_f32_16x16x32_bf16(a1, bfrag, acc[1][ct], 0, 0, 0);
        }
      }
    }
    __syncthreads();
  }
#undef STAGEW

#pragma unroll
  for (int ls = 0; ls < 2; ++ls)
#pragma unroll
    for (int ct = 0; ct < 3; ++ct) {
      int dg = g * 48 + ct * 16 + c15;
      float bv = bias[dg];
#pragma unroll
      for (int r = 0; r < 4; ++r) {
        int l = l0 + ls * 64 + w * 16 + g4 * 4 + r;
        size_t idx = (size_t)(b * 2048 + l) * 768 + dg;
        float vv = acc[ls][ct][r] + bv;
        vv = 0.5f * vv * (1.0f + erff(vv * 0.70710678f));
        out[idx] = x[idx] + vv;
      }
    }
}

// ---------------------------------------------------------------- layernorm f32-in (ln0 only)
__global__ __launch_bounds__(256) void ln_kernel(const float* __restrict__ a,
                                                 const float* __restrict__ g,
                                                 const float* __restrict__ be,
                                                 bf16* __restrict__ outb) {
  int w = threadIdx.x >> 6, lane = threadIdx.x & 63;
  size_t row = (size_t)blockIdx.x * 4 + w;
  const float* ar = a + row * 768;
  float4 v[3];
  float s = 0.f;
#pragma unroll
  for (int i = 0; i < 3; ++i) {
    int c = lane * 4 + i * 256;
    float4 vv = *(const float4*)(ar + c);
    v[i] = vv;
    s += vv.x + vv.y + vv.z + vv.w;
  }
#pragma unroll
  for (int st = 1; st < 64; st <<= 1) s += __shfl_xor(s, st);
  float mean = s * (1.0f / 768.0f);
  float s2 = 0.f;
#pragma unroll
  for (int i = 0; i < 3; ++i) {
    float dx = v[i].x - mean, dy = v[i].y - mean, dz = v[i].z - mean, dw = v[i].w - mean;
    s2 += dx * dx + dy * dy + dz * dz + dw * dw;
  }
#pragma unroll
  for (int st = 1; st < 64; st <<= 1) s2 += __shfl_xor(s2, st);
  float rstd = rsqrtf(s2 * (1.0f / 768.0f) + 1e-5f);
#pragma unroll
  for (int i = 0; i < 3; ++i) {
    int c = lane * 4 + i * 256;
    float4 gv = *(const float4*)(g + c);
    float4 bv = *(const float4*)(be + c);
    union { bf16 h[4]; uint2 u; } pk;
    pk.h[0] = __float2bfloat16((v[i].x - mean) * rstd * gv.x + bv.x);
    pk.h[1] = __float2bfloat16((v[i].y - mean) * rstd * gv.y + bv.y);
    pk.h[2] = __float2bfloat16((v[i].z - mean) * rstd * gv.z + bv.z);
    pk.h[3] = __float2bfloat16((v[i].w - mean) * rstd * gv.w + bv.w);
    *(uint2*)(outb + row * 768 + c) = pk.u;
  }
}

// ---------------------------------------------------------------- layernorm bf16-in + bf16 residual
template <int F32OUT>
__global__ __launch_bounds__(256) void ln_bf(const bf16* __restrict__ a,
                                             const bf16* __restrict__ r,
                                             const float* __restrict__ g,
                                             const float* __restrict__ be,
                                             bf16* __restrict__ outb,
                                             float* __restrict__ outf) {
  int w = threadIdx.x >> 6, lane = threadIdx.x & 63;
  size_t row = (size_t)blockIdx.x * 4 + w;
  const bf16* ar = a + row * 768;
  const bf16* rr = r + row * 768;
  float v[3][4];
  float s = 0.f;
#pragma unroll
  for (int i = 0; i < 3; ++i) {
    int c = lane * 4 + i * 256;
    union { uint2 u; uint16_t h[4]; } ua, urr;
    ua.u = *(const uint2*)(ar + c);
    urr.u = *(const uint2*)(rr + c);
#pragma unroll
    for (int j = 0; j < 4; ++j) {
      float x = __uint_as_float((uint32_t)ua.h[j] << 16) +
                __uint_as_float((uint32_t)urr.h[j] << 16);
      v[i][j] = x; s += x;
    }
  }
#pragma unroll
  for (int st = 1; st < 64; st <<= 1) s += __shfl_xor(s, st);
  float mean = s * (1.0f / 768.0f);
  float s2 = 0.f;
#pragma unroll
  for (int i = 0; i < 3; ++i)
#pragma unroll
    for (int j = 0; j < 4; ++j) {
      float d2 = v[i][j] - mean;
      s2 += d2 * d2;
    }
#pragma unroll
  for (int st = 1; st < 64; st <<= 1) s2 += __shfl_xor(s2, st);
  float rstd = rsqrtf(s2 * (1.0f / 768.0f) + 1e-5f);
#pragma unroll
  for (int i = 0; i < 3; ++i) {
    int c = lane * 4 + i * 256;
    float4 gv = *(const float4*)(g + c);
    float4 bv = *(const float4*)(be + c);
    float o0 = (v[i][0] - mean) * rstd * gv.x + bv.x;
    float o1 = (v[i][1] - mean) * rstd * gv.y + bv.y;
    float o2 = (v[i][2] - mean) * rstd * gv.z + bv.z;
    float o3 = (v[i][3] - mean) * rstd * gv.w + bv.w;
    union { bf16 h[4]; uint2 u; } pk;
    pk.h[0] = __float2bfloat16(o0); pk.h[1] = __float2bfloat16(o1);
    pk.h[2] = __float2bfloat16(o2); pk.h[3] = __float2bfloat16(o3);
    *(uint2*)(outb + row * 768 + c) = pk.u;
    if (F32OUT) {
      float4 of = {o0, o1, o2, o3};
      *(float4*)(outf + row * 768 + c) = of;
    }
  }
}

// ---------------------------------------------------------------- weight prep (per-layer)
__global__ __launch_bounds__(256) void prep_weights(const float* __restrict__ WqB,
                                                    const float* __restrict__ WkB,
                                                    const float* __restrict__ WvB,
                                                    const float* __restrict__ WoB,
                                                    const float* __restrict__ W1B,
                                                    const float* __restrict__ W2B,
                                                    const float* __restrict__ bqB,
                                                    const float* __restrict__ bkB,
                                                    const float* __restrict__ bvB,
                                                    bf16* __restrict__ wqkvb,
                                                    bf16* __restrict__ wob,
                                                    bf16* __restrict__ w1b,
                                                    bf16* __restrict__ w2b,
                                                    float* __restrict__ bqkv,
                                                    int l) {
  __shared__ float t[32][33];
  int tid = threadIdx.x;
  int tx = tid & 31, ty = tid >> 5;
  const float* wq = WqB + (size_t)l * 768 * 768;
  const float* wk = WkB + (size_t)l * 768 * 768;
  const float* wv = WvB + (size_t)l * 768 * 768;
  const float* wo = WoB + (size_t)l * 768 * 768;
  const float* w1 = W1B + (size_t)l * 768 * 3072;
  const float* w2 = W2B + (size_t)l * 3072 * 768;

  int blk = blockIdx.x;
  if (blk >= 6912) {
    int i = (blk - 6912) * 256 + tid;
    if (i < 2304)
      bqkv[i] = (i < 768) ? bqB[(size_t)l * 768 + i]
              : (i < 1536) ? bkB[(size_t)l * 768 + i - 768]
                           : bvB[(size_t)l * 768 + i - 1536];
    return;
  }
  if (blk < 1728) {
    int n0 = (blk % 72) * 32, k0 = (blk / 72) * 32;
    const float* src = (n0 < 768) ? wq : (n0 < 1536) ? wk : wv;
    int nn = (n0 >= 1536) ? (n0 - 1536) : (n0 >= 768 ? n0 - 768 : n0);
#pragma unroll
    for (int i = 0; i < 32; i += 8) t[ty + i][tx] = src[(size_t)(k0 + ty + i) * 768 + nn + tx];
    __syncthreads();
#pragma unroll
    for (int i = 0; i < 32; i += 8)
      wqkvb[(size_t)(n0 + ty + i) * 768 + k0 + tx] = __float2bfloat16(t[tx][ty + i]);
    return;
  }
  blk -= 1728;
  if (blk < 576) {
    int c0 = (blk % 24) * 32, r0 = (blk / 24) * 32;
#pragma unroll
    for (int i = 0; i < 32; i += 8) t[ty + i][tx] = wo[(size_t)(r0 + ty + i) * 768 + c0 + tx];
    __syncthreads();
#pragma unroll
    for (int i = 0; i < 32; i += 8)
      wob[(size_t)(c0 + ty + i) * 768 + r0 + tx] = __float2bfloat16(t[tx][ty + i]);
    return;
  }
  blk -= 576;
  if (blk < 2304) {
    int c0 = (blk % 96) * 32, r0 = (blk / 96) * 32;
#pragma unroll
    for (int i = 0; i < 32; i += 8) t[ty + i][tx] = w1[(size_t)(r0 + ty + i) * 3072 + c0 + tx];
    __syncthreads();
#pragma unroll
    for (int i = 0; i < 32; i += 8)
      w1b[(size_t)(c0 + ty + i) * 768 + r0 + tx] = __float2bfloat16(t[tx][ty + i]);
    return;
  }
  blk -= 2304;
  {
    int c0 = (blk % 24) * 32, r0 = (blk / 24) * 32;
#pragma unroll
    for (int i = 0; i < 32; i += 8) t[ty + i][tx] = w2[(size_t)(r0 + ty + i) * 768 + c0 + tx];
    __syncthreads();
#pragma unroll
    for (int i = 0; i < 32; i += 8)
      w2b[(size_t)(c0 + ty + i) * 3072 + r0 + tx] = __float2bfloat16(t[tx][ty + i]);
  }
}

// ---------------------------------------------------------------- bf16 MFMA GEMM (BK templated)
template <int BM, int BN, int BK, int GELU, int BF16OUT, int VOUT = 0>
__global__ __launch_bounds__(256) void gemm_bf16(const bf16* __restrict__ A,
                                                 const bf16* __restrict__ BT,
                                                 const float* __restrict__ bias,
                                                 void* __restrict__ Cout,
                                                 int N, int Kd,
                                                 bf16* __restrict__ vTout = nullptr) {
  constexpr int WM = BM / 2, MF = WM / 16;
  constexpr int WN = BN / 2, FN = WN / 16;
  constexpr int KF = BK / 32;
  constexpr int ROWB = BK * 2;
  constexpr int RPC = 1024 / ROWB;
  constexpr int NCH = BM * BK / 512;
  __shared__ bf16 As[BM * BK];
  __shared__ bf16 Bs[BN * BK];
  const int tid = threadIdx.x, w = tid >> 6, lane = tid & 63;
  int gx = gridDim.x;
  int flat = blockIdx.x + gx * blockIdx.y;
  int cpx = (gx * gridDim.y) >> 3;
  int sw = (flat & 7) * cpx + (flat >> 3);
  const int bn = sw % gx, bm = sw / gx;
  const int wr = w >> 1, wc = w & 1;
  const int c15 = lane & 15, g4 = lane >> 4;
  const int rowInC = lane / (ROWB / 16);
  const int colb = (lane % (ROWB / 16)) * 16;

  f32x4 acc[MF][FN];
  const f32x4 vzero = {0.f, 0.f, 0.f, 0.f};
#pragma unroll
  for (int i = 0; i < MF; ++i)
#pragma unroll
    for (int j = 0; j < FN; ++j) acc[i][j] = vzero;

  const char* Ab = (const char*)A;
  const char* Bb = (const char*)BT;

  for (int k0 = 0; k0 < Kd; k0 += BK) {
#pragma unroll
    for (int i = 0; i < NCH / 4; ++i) {
      int t = w + 4 * i;
      int row = t * RPC + rowInC;
      gload16(Ab + ((size_t)(bm * BM + row) * Kd + k0) * 2 + (colb ^ ((row & 7) << 4)),
              (char*)As + t * 1024);
    }
#pragma unroll
    for (int i = 0; i < (BN * BK / 512) / 4; ++i) {
      int t = w + 4 * i;
      int row = t * RPC + rowInC;
      gload16(Bb + ((size_t)(bn * BN + row) * Kd + k0) * 2 + (colb ^ ((row & 7) << 4)),
              (char*)Bs + t * 1024);
    }
    __syncthreads();
    if constexpr (KF <= 2) {
      bf16x8 af[MF][KF], bfr[FN][KF];
#pragma unroll
      for (int kf = 0; kf < KF; ++kf) {
        int kbyte = kf * 64 + g4 * 16;
#pragma unroll
        for (int mf = 0; mf < MF; ++mf) {
          int row = wr * WM + mf * 16 + c15;
          af[mf][kf] = *(const bf16x8*)((const char*)As + row * ROWB + (kbyte ^ ((row & 7) << 4)));
        }
#pragma unroll
        for (int fn = 0; fn < FN; ++fn) {
          int row = wc * WN + fn * 16 + c15;
          bfr[fn][kf] = *(const bf16x8*)((const char*)Bs + row * ROWB + (kbyte ^ ((row & 7) << 4)));
        }
      }
      __builtin_amdgcn_s_setprio(1);
#pragma unroll
      for (int mf = 0; mf < MF; ++mf)
#pragma unroll
        for (int fn = 0; fn < FN; ++fn)
#pragma unroll
          for (int kf = 0; kf < KF; ++kf)
            acc[mf][fn] = __builtin_amdgcn_mfma_f32_16x16x32_bf16(af[mf][kf], bfr[fn][kf], acc[mf][fn], 0, 0, 0);
      __builtin_amdgcn_s_setprio(0);
    } else {
      // per-kf fragment loads to cap register pressure at large BK
#pragma unroll
      for (int kf = 0; kf < KF; ++kf) {
        int kbyte = kf * 64 + g4 * 16;
        bf16x8 af[MF], bfr[FN];
#pragma unroll
        for (int mf = 0; mf < MF; ++mf) {
          int row = wr * WM + mf * 16 + c15;
          af[mf] = *(const bf16x8*)((const char*)As + row * ROWB + (kbyte ^ ((row & 7) << 4)));
        }
#pragma unroll
        for (int fn = 0; fn < FN; ++fn) {
          int row = wc * WN + fn * 16 + c15;
          bfr[fn] = *(const bf16x8*)((const char*)Bs + row * ROWB + (kbyte ^ ((row & 7) << 4)));
        }
        __builtin_amdgcn_s_setprio(1);
#pragma unroll
        for (int mf = 0; mf < MF; ++mf)
#pragma unroll
          for (int fn = 0; fn < FN; ++fn)
            acc[mf][fn] = __builtin_amdgcn_mfma_f32_16x16x32_bf16(af[mf], bfr[fn], acc[mf][fn], 0, 0, 0);
        __builtin_amdgcn_s_setprio(0);
      }
    }
    __syncthreads();
  }
#pragma unroll
  for (int fn = 0; fn < FN; ++fn) {
    int col = bn * BN + wc * WN + fn * 16 + c15;
    float bv = bias[col];
#pragma unroll
    for (int mf = 0; mf < MF; ++mf) {
#pragma unroll
      for (int r = 0; r < 4; ++r) {
        int row = bm * BM + wr * WM + mf * 16 + g4 * 4 + r;
        float vv = acc[mf][fn][r] + bv;
        if (GELU) vv = 0.5f * vv * (1.0f + erff(vv * 0.70710678f));
        if (BF16OUT) {
          if (VOUT && col >= 1536) {
            int hd2 = col - 1536, hh = hd2 >> 6, dd = hd2 & 63;
            int bb = row >> 11, ll = row & 2047;
            vTout[((size_t)((bb * 12 + hh) * 64 + dd) << 11) + ll] = __float2bfloat16(vv);
          } else {
            ((bf16*)Cout)[(size_t)row * N + col] = __float2bfloat16(vv);
          }
        } else {
          ((float*)Cout)[(size_t)row * N + col] = vv;
        }
      }
    }
  }
}

// ---------------------------------------------------------------- flash attention v7
__global__ __launch_bounds__(256) void attn_mfma(const bf16* __restrict__ qkv,
                                                 const bf16* __restrict__ vT,
                                                 bf16* __restrict__ ob) {
  int bid = blockIdx.x + 32 * (blockIdx.y + 12 * blockIdx.z);
  int wgid = (bid & 7) * 96 + (bid >> 3);
  const int q0 = (wgid & 31) * 64;
  int bh = wgid >> 5;
  const int h = bh % 12, b = bh / 12;

  const int tid = threadIdx.x, w = tid >> 6, lane = tid & 63;
  const int c15 = lane & 15, g4 = lane >> 4;
  const int lrow8 = lane >> 3;
  const int cb = (lane & 7) * 16;
  __shared__ bf16 Kl[2][4096];
  __shared__ bf16 Vl[3][4096];
  __shared__ bf16 Pl[4096];

  const f32x4 vzero = {0.f, 0.f, 0.f, 0.f};
  const char* qp = (const char*)qkv + (((size_t)(b * 2048 + q0 + w * 16 + c15)) * 2304 + h * 64) * 2;
  bf16x8 qa0 = *(const bf16x8*)(qp + g4 * 16);
  bf16x8 qa1 = *(const bf16x8*)(qp + 64 + g4 * 16);

  bf16x8 b_one;
#pragma unroll
  for (int i = 0; i < 8; ++i) b_one[i] = (__bf16)1.0f;

  f32x4 o[4], o5;
#pragma unroll
  for (int i = 0; i < 4; ++i) o[i] = vzero;
  o5 = vzero;
  float m = -1e30f;
  const float SC2 = 0.18033688f;
  const float THR = 11.54f;

  const char* kgb = (const char*)qkv + (((size_t)(b * 2048)) * 2304 + 768 + h * 64) * 2;
  const char* vgb = (const char*)vT + ((size_t)((b * 12 + h) * 64) * 2048) * 2;
  char* Plw = (char*)Pl + w * 2048;

  const int rr0 = w * 8 + lrow8;
  const int swz = cb ^ (lrow8 << 4);
  const char* ka0 = kgb + (size_t)rr0 * 4608 + swz;
  const char* ka1 = ka0 + 32 * 4608;
  const char* va0 = vgb + (size_t)rr0 * 4096 + swz;
  const char* va1 = va0 + 32 * 4096;
  char* kd0 = (char*)Kl[0] + w * 1024;
  char* vd0 = (char*)Vl[0] + w * 1024;

#define STAGE_K(kt, bufi)                                                      \
  {                                                                            \
    size_t ko = (size_t)(kt) * 294912;                                         \
    int lo = (bufi) * 8192;                                                    \
    gload16(ka0 + ko, kd0 + lo);                                               \
    gload16(ka1 + ko, kd0 + lo + 4096);                                        \
  }
#define STAGE_V(kt, bufi)                                                      \
  {                                                                            \
    size_t vo = (size_t)(kt) * 128;                                            \
    int lo = (bufi) * 8192;                                                    \
    gload16(va0 + vo, vd0 + lo);                                               \
    gload16(va1 + vo, vd0 + lo + 4096);                                        \
  }

#define DO_QK(SC, kbuf)                                                        \
  {                                                                            \
    const char* Kc = (const char*)Kl[kbuf];                                    \
    __builtin_amdgcn_s_setprio(1);                                             \
    _Pragma("unroll")                                                          \
    for (int fn = 0; fn < 4; ++fn) {                                           \
      int key = fn * 16 + c15;                                                 \
      const char* kr = Kc + key * 128;                                         \
      int swk = (key & 7) << 4;                                                \
      bf16x8 kb0 = *(const bf16x8*)(kr + ((g4 * 16) ^ swk));                   \
      bf16x8 kb1 = *(const bf16x8*)(kr + ((64 + g4 * 16) ^ swk));              \
      f32x4 s = __builtin_amdgcn_mfma_f32_16x16x32_bf16(kb0, qa0, vzero, 0, 0, 0); \
      s = __builtin_amdgcn_mfma_f32_16x16x32_bf16(kb1, qa1, s, 0, 0, 0);       \
      SC[fn] = s;                                                              \
    }                                                                          \
    __builtin_amdgcn_s_setprio(0);                                             \
  }

#define DO_SMPV(SC, vbuf)                                                      \
  {                                                                            \
    float pm = fmaxf(                                                          \
        fmaxf(fmaxf(fmaxf(SC[0][0], SC[0][1]), fmaxf(SC[0][2], SC[0][3])),     \
              fmaxf(fmaxf(SC[1][0], SC[1][1]), fmaxf(SC[1][2], SC[1][3]))),    \
        fmaxf(fmaxf(fmaxf(SC[2][0], SC[2][1]), fmaxf(SC[2][2], SC[2][3])),     \
              fmaxf(fmaxf(SC[3][0], SC[3][1]), fmaxf(SC[3][2], SC[3][3]))));   \
    int ok = (pm * SC2 <= m + THR) ? 1 : 0;                                    \
    if (!__all(ok)) {                                                          \
      float tm = pm;                                                           \
      tm = fmaxf(tm, __shfl_xor(tm, 16));                                      \
      tm = fmaxf(tm, __shfl_xor(tm, 32));                                      \
      float mn = fmaxf(m, tm * SC2);                                           \
      float alpha = exp2f(m - mn);                                             \
      m = mn;                                                                  \
      _Pragma("unroll")                                                        \
      for (int r = 0; r < 4; ++r) {                                            \
        float ar = __shfl(alpha, g4 * 4 + r);                                  \
        o[0][r] *= ar; o[1][r] *= ar; o[2][r] *= ar; o[3][r] *= ar;            \
        o5[r] *= ar;                                                           \
      }                                                                        \
    }                                                                          \
    {                                                                          \
      char* prow = Plw + c15 * 128;                                            \
      int swp = (c15 & 7) << 4;                                                \
      _Pragma("unroll")                                                        \
      for (int fn = 0; fn < 4; ++fn) {                                         \
        union { bf16 hh[4]; uint2 u; } pk;                                     \
        _Pragma("unroll")                                                      \
        for (int r = 0; r < 4; ++r)                                            \
          pk.hh[r] = __float2bfloat16(exp2f(fmaf(SC[fn][r], SC2, -m)));        \
        *(uint2*)(prow + ((fn * 32 + g4 * 8) ^ swp)) = pk.u;                   \
      }                                                                        \
    }                                                                          \
    {                                                                          \
      const char* pr = Plw + c15 * 128;                                        \
      int swp2 = (c15 & 7) << 4;                                               \
      bf16x8 pa0 = *(const bf16x8*)(pr + ((g4 * 16) ^ swp2));                  \
      bf16x8 pa1 = *(const bf16x8*)(pr + ((64 + g4 * 16) ^ swp2));             \
      const char* Vc = (const char*)Vl[vbuf];                                  \
      __builtin_amdgcn_s_setprio(1);                                           \
      _Pragma("unroll")                                                        \
      for (int fh = 0; fh < 4; ++fh) {                                         \
        int hd = fh * 16 + c15;                                                \
        const char* vr = Vc + hd * 128;                                        \
        int swv = (hd & 7) << 4;                                               \
        bf16x8 vb0 = *(const bf16x8*)(vr + ((g4 * 16) ^ swv));                 \
        bf16x8 vb1 = *(const bf16x8*)(vr + ((64 + g4 * 16) ^ swv));            \
        o[fh] = __builtin_amdgcn_mfma_f32_16x16x32_bf16(pa0, vb0, o[fh], 0, 0, 0); \
        o[fh] = __builtin_amdgcn_mfma_f32_16x16x32_bf16(pa1, vb1, o[fh], 0, 0, 0); \
      }                                                                        \
      o5 = __builtin_amdgcn_mfma_f32_16x16x32_bf16(pa0, b_one, o5, 0, 0, 0);   \
      o5 = __builtin_amdgcn_mfma_f32_16x16x32_bf16(pa1, b_one, o5, 0, 0, 0);   \
      __builtin_amdgcn_s_setprio(0);                                           \
    }                                                                          \
  }

  STAGE_K(0, 0); STAGE_K(1, 1); STAGE_V(0, 0); STAGE_V(1, 1);
  __syncthreads();

  f32x4 scA[4], scB[4];
  DO_QK(scA, 0);

#define ITER(kt, SCUR, SNXT)                                                   \
  {                                                                            \
    if ((kt) + 2 < 32) {                                                       \
      STAGE_K((kt) + 2, (kt) & 1);                                             \
      STAGE_V((kt) + 2, ((kt) + 2) % 3);                                       \
    }                                                                          \
    if ((kt) + 1 < 32) DO_QK(SNXT, ((kt) + 1) & 1);                            \
    DO_SMPV(SCUR, (kt) % 3);                                                   \
    __syncthreads();                                                           \
  }

#pragma unroll 2
  for (int kt2 = 0; kt2 < 32; kt2 += 2) {
    ITER(kt2, scA, scB);
    ITER(kt2 + 1, scB, scA);
  }
#undef ITER
#undef DO_SMPV
#undef DO_QK
#undef STAGE_K
#undef STAGE_V

#pragma unroll
  for (int r = 0; r < 4; ++r) {
    float inv = 1.0f / o5[r];
    size_t row = (size_t)(b * 2048 + q0 + w * 16 + g4 * 4 + r);
#pragma unroll
    for (int fh = 0; fh < 4; ++fh)
      ob[row * 768 + h * 64 + fh * 16 + c15] = __float2bfloat16(o[fh][r] * inv);
  }
}

// ----------------------------------------------------------------
extern "C" void kernel_launch(void* const* d_in, const int* in_sizes, int n_in,
                              void* d_out, int out_size, void* d_ws, size_t ws_size,
                              hipStream_t stream) {
  const float* x      = (const float*)d_in[0];
  const float* pcw    = (const float*)d_in[1];
  const float* pcb    = (const float*)d_in[2];
  const float* ln0_g  = (const float*)d_in[3];
  const float* ln0_b  = (const float*)d_in[4];
  const float* Wq     = (const float*)d_in[5];
  const float* bq     = (const float*)d_in[6];
  const float* Wk     = (const float*)d_in[7];
  const float* bk     = (const float*)d_in[8];
  const float* Wv     = (const float*)d_in[9];
  const float* bv     = (const float*)d_in[10];
  const float* Wo     = (const float*)d_in[11];
  const float* bo     = (const float*)d_in[12];
  const float* ln1_g  = (const float*)d_in[13];
  const float* ln1_b  = (const float*)d_in[14];
  const float* W1     = (const float*)d_in[15];
  const float* b1     = (const float*)d_in[16];
  const float* W2     = (const float*)d_in[17];
  const float* b2     = (const float*)d_in[18];
  const float* ln2_g  = (const float*)d_in[19];
  const float* ln2_b  = (const float*)d_in[20];

  const size_t MDB = (size_t)M_TOK * D_ * 4;
  char* W = (char*)d_ws;
  float* tmp  = (float*)(W + MDB);
  char*  big  = W + 2 * MDB;
  bf16*  qkv  = (bf16*)big;
  bf16*  ff   = (bf16*)big;
  bf16*  wT2  = (bf16*)big;
  bf16*  tmp_bf = (bf16*)W;
  char* p = W + 2 * MDB + 25165824;
  bf16* h_bf  = (bf16*)p; p += (size_t)M_TOK * D_ * 2;
  bf16* obuf  = (bf16*)p; p += (size_t)M_TOK * D_ * 2;
  bf16* vT    = (bf16*)p; p += (size_t)M_TOK * D_ * 2;
  bf16* wqkvb = (bf16*)p; p += (size_t)2304 * 768 * 2;
  bf16* wob   = (bf16*)p; p += (size_t)768 * 768 * 2;
  bf16* w1b   = (bf16*)p; p += (size_t)3072 * 768 * 2;
  bf16* w2b   = (bf16*)p; p += (size_t)768 * 3072 * 2;
  float* bqkv = (float*)p;

  convw_kernel<<<24576, 256, 0, stream>>>(pcw, wT2);
  conv_mfma<<<512, 256, 0, stream>>>(x, wT2, pcb, tmp);
  ln_kernel<<<M_TOK / 4, 256, 0, stream>>>(tmp, ln0_g, ln0_b, h_bf);

  for (int l = 0; l < NL_; ++l) {
    prep_weights<<<6921, 256, 0, stream>>>(Wq, Wk, Wv, Wo, W1, W2, bq, bk, bv,
                                           wqkvb, wob, w1b, w2b, bqkv, l);

    gemm_bf16<128, 128, 128, 0, 1, 1><<<dim3(18, 32), 256, 0, stream>>>(h_bf, wqkvb, bqkv, qkv, 2304, 768, vT);
    attn_mfma<<<dim3(32, 12, 2), 256, 0, stream>>>(qkv, vT, obuf);
    gemm_bf16<64, 64, 128, 0, 1><<<dim3(12, 64), 256, 0, stream>>>(obuf, wob, bo + (size_t)l * D_, tmp_bf, 768, 768);
    ln_bf<0><<<M_TOK / 4, 256, 0, stream>>>(tmp_bf, h_bf, ln1_g + (size_t)l * D_, ln1_b + (size_t)l * D_, h_bf, nullptr);
    gemm_bf16<128, 128, 128, 1, 1><<<dim3(24, 32), 256, 0, stream>>>(h_bf, w1b, b1 + (size_t)l * F_, ff, 3072, 768);
    gemm_bf16<64, 64, 128, 0, 1><<<dim3(12, 64), 256, 0, stream>>>(ff, w2b, b2 + (size_t)l * D_, tmp_bf, 768, 3072);
    if (l == NL_ - 1)
      ln_bf<1><<<M_TOK / 4, 256, 0, stream>>>(tmp_bf, h_bf, ln2_g + (size_t)l * D_, ln2_b + (size_t)l * D_, h_bf, (float*)d_out);
    else
      ln_bf<0><<<M_TOK / 4, 256, 0, stream>>>(tmp_bf, h_bf, ln2_g + (size_t)l * D_, ln2_b + (size_t)l * D_, h_bf, nullptr);
  }
}

// Round 19
// 2267.734 us; speedup vs baseline: 1.0769x; 1.0769x over previous
//
#include <hip/hip_runtime.h>
#include <hip/hip_bf16.h>
#include <stdint.h>

#define B_ 2
#define L_ 2048
#define D_ 768
#define H_ 12
#define F_ 3072
#define NL_ 12
#define K_ 128
#define G_ 16
#define HD_ 64
#define CPG_ 48
#define M_TOK (B_*L_)
#define SCALE_ 0.125f

typedef __hip_bfloat16 bf16;
typedef __bf16 bf16x8 __attribute__((ext_vector_type(8)));
typedef float f32x4 __attribute__((ext_vector_type(4)));

__device__ __forceinline__ void gload16(const void* g, void* l) {
  __builtin_amdgcn_global_load_lds((const __attribute__((address_space(1))) void*)g,
                                   (__attribute__((address_space(3))) void*)l, 16, 0, 0);
}

// ---------------------------------------------------------------- conv weight pre-transpose
__global__ __launch_bounds__(256) void convw_kernel(const float* __restrict__ w,
                                                    bf16* __restrict__ wT2) {
  int idx = blockIdx.x * 256 + threadIdx.x;
  int ci = idx & 63;
  int row = idx >> 6;
  int d = row % 48;
  int t2 = row / 48;
  int kk = t2 & 127;
  int g = t2 >> 7;
  float v = (ci < 48) ? w[(((size_t)(g * 48 + d) * 48) + ci) * 128 + kk] : 0.f;
  wT2[idx] = __float2bfloat16(v);
}

// ---------------------------------------------------------------- conv via MFMA (dbuf weights)
__global__ __launch_bounds__(256) void conv_mfma(const float* __restrict__ x,
                                                 const bf16* __restrict__ wT2,
                                                 const float* __restrict__ bias,
                                                 float* __restrict__ out) {
  int flat = blockIdx.x;
  int wgid = (flat & 7) * 64 + (flat >> 3);
  const int g = wgid >> 5;
  int rem = wgid & 31;
  const int l0 = (rem & 15) * 128;
  const int b = rem >> 4;

  const int tid = threadIdx.x, w = tid >> 6, lane = tid & 63;
  const int c15 = lane & 15, g4 = lane >> 4;
  __shared__ __align__(16) bf16 win[256 * 64];
  __shared__ __align__(16) bf16 Wl[2][2 * 48 * 64];

  {
    int lg = l0 - 64 + tid;
    char* dst = (char*)win + tid * 128;
    int swr = (tid & 7) << 4;
    uint4 z4 = {0u, 0u, 0u, 0u};
    if ((unsigned)lg < 2048u) {
      const float* srow = x + ((size_t)(b * 2048 + lg) * 768 + g * 48);
#pragma unroll
      for (int c = 0; c < 6; ++c) {
        float4 v0 = *(const float4*)(srow + c * 8);
        float4 v1 = *(const float4*)(srow + c * 8 + 4);
        union { bf16 h[8]; uint4 u; } uu;
        uu.h[0] = __float2bfloat16(v0.x); uu.h[1] = __float2bfloat16(v0.y);
        uu.h[2] = __float2bfloat16(v0.z); uu.h[3] = __float2bfloat16(v0.w);
        uu.h[4] = __float2bfloat16(v1.x); uu.h[5] = __float2bfloat16(v1.y);
        uu.h[6] = __float2bfloat16(v1.z); uu.h[7] = __float2bfloat16(v1.w);
        *(uint4*)(dst + ((c * 16) ^ swr)) = uu.u;
      }
    } else {
#pragma unroll
      for (int c = 0; c < 6; ++c) *(uint4*)(dst + ((c * 16) ^ swr)) = z4;
    }
    *(uint4*)(dst + (96 ^ swr)) = z4;
    *(uint4*)(dst + (112 ^ swr)) = z4;
  }

  const char* wbase = (const char*)wT2 + (size_t)g * 128 * 48 * 128;
  const int coff = w * 3072;
#define STAGEW(kp, bufi)                                                                   \
  {                                                                                        \
    _Pragma("unroll")                                                                      \
    for (int i = 0; i < 3; ++i) {                                                          \
      int c = coff + i * 1024 + (lane << 4);                                               \
      int row96 = c >> 7;                                                                  \
      int s = row96 / 48;                                                                  \
      int d = row96 - s * 48;                                                              \
      int cb2 = c & 127;                                                                   \
      gload16(wbase + ((size_t)((2 * (kp) + s) * 48 + d)) * 128 + (cb2 ^ ((d & 7) << 4)),  \
              (char*)Wl[bufi] + coff + i * 1024);                                          \
    }                                                                                      \
  }

  f32x4 acc[2][3];
  const f32x4 vzero = {0.f, 0.f, 0.f, 0.f};
#pragma unroll
  for (int i = 0; i < 2; ++i)
#pragma unroll
    for (int j = 0; j < 3; ++j) acc[i][j] = vzero;

  STAGEW(0, 0);
  __syncthreads();

  for (int kp = 0; kp < 64; ++kp) {
    int cur = kp & 1;
    if (kp + 1 < 64) STAGEW(kp + 1, cur ^ 1);
    const char* Wc = (const char*)Wl[cur];
#pragma unroll
    for (int s = 0; s < 2; ++s) {
      int kk = 2 * kp + s;
#pragma unroll
      for (int cb = 0; cb < 2; ++cb) {
        int a0r = w * 16 + c15 + kk;
        int a1r = 64 + a0r;
        bf16x8 a0 = *(const bf16x8*)((const char*)win + a0r * 128 + ((cb * 64 + g4 * 16) ^ ((a0r & 7) << 4)));
        bf16x8 a1 = *(const bf16x8*)((const char*)win + a1r * 128 + ((cb * 64 + g4 * 16) ^ ((a1r & 7) << 4)));
#pragma unroll
        for (int ct = 0; ct < 3; ++ct) {
          int d = ct * 16 + c15;
          bf16x8 bfrag = *(const bf16x8*)(Wc + s * 6144 + d * 128 +
                                          ((cb * 64 + g4 * 16) ^ ((d & 7) << 4)));
          acc[0][ct] = __builtin_amdgcn_mfma_f32_16x16x32_bf16(a0, bfrag, acc[0][ct], 0, 0, 0);
          acc[1][ct] = __builtin_amdgcn_mfma_f32_16x16x32_bf16(a1, bfrag, acc[1][ct], 0, 0, 0);
        }
      }
    }
    __syncthreads();
  }
#undef STAGEW

#pragma unroll
  for (int ls = 0; ls < 2; ++ls)
#pragma unroll
    for (int ct = 0; ct < 3; ++ct) {
      int dg = g * 48 + ct * 16 + c15;
      float bv = bias[dg];
#pragma unroll
      for (int r = 0; r < 4; ++r) {
        int l = l0 + ls * 64 + w * 16 + g4 * 4 + r;
        size_t idx = (size_t)(b * 2048 + l) * 768 + dg;
        float vv = acc[ls][ct][r] + bv;
        vv = 0.5f * vv * (1.0f + erff(vv * 0.70710678f));
        out[idx] = x[idx] + vv;
      }
    }
}

// ---------------------------------------------------------------- layernorm f32-in (ln0 only)
__global__ __launch_bounds__(256) void ln_kernel(const float* __restrict__ a,
                                                 const float* __restrict__ g,
                                                 const float* __restrict__ be,
                                                 bf16* __restrict__ outb) {
  int w = threadIdx.x >> 6, lane = threadIdx.x & 63;
  size_t row = (size_t)blockIdx.x * 4 + w;
  const float* ar = a + row * 768;
  float4 v[3];
  float s = 0.f;
#pragma unroll
  for (int i = 0; i < 3; ++i) {
    int c = lane * 4 + i * 256;
    float4 vv = *(const float4*)(ar + c);
    v[i] = vv;
    s += vv.x + vv.y + vv.z + vv.w;
  }
#pragma unroll
  for (int st = 1; st < 64; st <<= 1) s += __shfl_xor(s, st);
  float mean = s * (1.0f / 768.0f);
  float s2 = 0.f;
#pragma unroll
  for (int i = 0; i < 3; ++i) {
    float dx = v[i].x - mean, dy = v[i].y - mean, dz = v[i].z - mean, dw = v[i].w - mean;
    s2 += dx * dx + dy * dy + dz * dz + dw * dw;
  }
#pragma unroll
  for (int st = 1; st < 64; st <<= 1) s2 += __shfl_xor(s2, st);
  float rstd = rsqrtf(s2 * (1.0f / 768.0f) + 1e-5f);
#pragma unroll
  for (int i = 0; i < 3; ++i) {
    int c = lane * 4 + i * 256;
    float4 gv = *(const float4*)(g + c);
    float4 bv = *(const float4*)(be + c);
    union { bf16 h[4]; uint2 u; } pk;
    pk.h[0] = __float2bfloat16((v[i].x - mean) * rstd * gv.x + bv.x);
    pk.h[1] = __float2bfloat16((v[i].y - mean) * rstd * gv.y + bv.y);
    pk.h[2] = __float2bfloat16((v[i].z - mean) * rstd * gv.z + bv.z);
    pk.h[3] = __float2bfloat16((v[i].w - mean) * rstd * gv.w + bv.w);
    *(uint2*)(outb + row * 768 + c) = pk.u;
  }
}

// ---------------------------------------------------------------- layernorm bf16-in + bf16 residual
template <int F32OUT>
__global__ __launch_bounds__(256) void ln_bf(const bf16* __restrict__ a,
                                             const bf16* __restrict__ r,
                                             const float* __restrict__ g,
                                             const float* __restrict__ be,
                                             bf16* __restrict__ outb,
                                             float* __restrict__ outf) {
  int w = threadIdx.x >> 6, lane = threadIdx.x & 63;
  size_t row = (size_t)blockIdx.x * 4 + w;
  const bf16* ar = a + row * 768;
  const bf16* rr = r + row * 768;
  float v[3][4];
  float s = 0.f;
#pragma unroll
  for (int i = 0; i < 3; ++i) {
    int c = lane * 4 + i * 256;
    union { uint2 u; uint16_t h[4]; } ua, urr;
    ua.u = *(const uint2*)(ar + c);
    urr.u = *(const uint2*)(rr + c);
#pragma unroll
    for (int j = 0; j < 4; ++j) {
      float x = __uint_as_float((uint32_t)ua.h[j] << 16) +
                __uint_as_float((uint32_t)urr.h[j] << 16);
      v[i][j] = x; s += x;
    }
  }
#pragma unroll
  for (int st = 1; st < 64; st <<= 1) s += __shfl_xor(s, st);
  float mean = s * (1.0f / 768.0f);
  float s2 = 0.f;
#pragma unroll
  for (int i = 0; i < 3; ++i)
#pragma unroll
    for (int j = 0; j < 4; ++j) {
      float d2 = v[i][j] - mean;
      s2 += d2 * d2;
    }
#pragma unroll
  for (int st = 1; st < 64; st <<= 1) s2 += __shfl_xor(s2, st);
  float rstd = rsqrtf(s2 * (1.0f / 768.0f) + 1e-5f);
#pragma unroll
  for (int i = 0; i < 3; ++i) {
    int c = lane * 4 + i * 256;
    float4 gv = *(const float4*)(g + c);
    float4 bv = *(const float4*)(be + c);
    float o0 = (v[i][0] - mean) * rstd * gv.x + bv.x;
    float o1 = (v[i][1] - mean) * rstd * gv.y + bv.y;
    float o2 = (v[i][2] - mean) * rstd * gv.z + bv.z;
    float o3 = (v[i][3] - mean) * rstd * gv.w + bv.w;
    union { bf16 h[4]; uint2 u; } pk;
    pk.h[0] = __float2bfloat16(o0); pk.h[1] = __float2bfloat16(o1);
    pk.h[2] = __float2bfloat16(o2); pk.h[3] = __float2bfloat16(o3);
    *(uint2*)(outb + row * 768 + c) = pk.u;
    if (F32OUT) {
      float4 of = {o0, o1, o2, o3};
      *(float4*)(outf + row * 768 + c) = of;
    }
  }
}

// ---------------------------------------------------------------- weight prep (per-layer)
__global__ __launch_bounds__(256) void prep_weights(const float* __restrict__ WqB,
                                                    const float* __restrict__ WkB,
                                                    const float* __restrict__ WvB,
                                                    const float* __restrict__ WoB,
                                                    const float* __restrict__ W1B,
                                                    const float* __restrict__ W2B,
                                                    const float* __restrict__ bqB,
                                                    const float* __restrict__ bkB,
                                                    const float* __restrict__ bvB,
                                                    bf16* __restrict__ wqkvb,
                                                    bf16* __restrict__ wob,
                                                    bf16* __restrict__ w1b,
                                                    bf16* __restrict__ w2b,
                                                    float* __restrict__ bqkv,
                                                    int l) {
  __shared__ float t[32][33];
  int tid = threadIdx.x;
  int tx = tid & 31, ty = tid >> 5;
  const float* wq = WqB + (size_t)l * 768 * 768;
  const float* wk = WkB + (size_t)l * 768 * 768;
  const float* wv = WvB + (size_t)l * 768 * 768;
  const float* wo = WoB + (size_t)l * 768 * 768;
  const float* w1 = W1B + (size_t)l * 768 * 3072;
  const float* w2 = W2B + (size_t)l * 3072 * 768;

  int blk = blockIdx.x;
  if (blk >= 6912) {
    int i = (blk - 6912) * 256 + tid;
    if (i < 2304)
      bqkv[i] = (i < 768) ? bqB[(size_t)l * 768 + i]
              : (i < 1536) ? bkB[(size_t)l * 768 + i - 768]
                           : bvB[(size_t)l * 768 + i - 1536];
    return;
  }
  if (blk < 1728) {
    int n0 = (blk % 72) * 32, k0 = (blk / 72) * 32;
    const float* src = (n0 < 768) ? wq : (n0 < 1536) ? wk : wv;
    int nn = (n0 >= 1536) ? (n0 - 1536) : (n0 >= 768 ? n0 - 768 : n0);
#pragma unroll
    for (int i = 0; i < 32; i += 8) t[ty + i][tx] = src[(size_t)(k0 + ty + i) * 768 + nn + tx];
    __syncthreads();
#pragma unroll
    for (int i = 0; i < 32; i += 8)
      wqkvb[(size_t)(n0 + ty + i) * 768 + k0 + tx] = __float2bfloat16(t[tx][ty + i]);
    return;
  }
  blk -= 1728;
  if (blk < 576) {
    int c0 = (blk % 24) * 32, r0 = (blk / 24) * 32;
#pragma unroll
    for (int i = 0; i < 32; i += 8) t[ty + i][tx] = wo[(size_t)(r0 + ty + i) * 768 + c0 + tx];
    __syncthreads();
#pragma unroll
    for (int i = 0; i < 32; i += 8)
      wob[(size_t)(c0 + ty + i) * 768 + r0 + tx] = __float2bfloat16(t[tx][ty + i]);
    return;
  }
  blk -= 576;
  if (blk < 2304) {
    int c0 = (blk % 96) * 32, r0 = (blk / 96) * 32;
#pragma unroll
    for (int i = 0; i < 32; i += 8) t[ty + i][tx] = w1[(size_t)(r0 + ty + i) * 3072 + c0 + tx];
    __syncthreads();
#pragma unroll
    for (int i = 0; i < 32; i += 8)
      w1b[(size_t)(c0 + ty + i) * 768 + r0 + tx] = __float2bfloat16(t[tx][ty + i]);
    return;
  }
  blk -= 2304;
  {
    int c0 = (blk % 24) * 32, r0 = (blk / 24) * 32;
#pragma unroll
    for (int i = 0; i < 32; i += 8) t[ty + i][tx] = w2[(size_t)(r0 + ty + i) * 768 + c0 + tx];
    __syncthreads();
#pragma unroll
    for (int i = 0; i < 32; i += 8)
      w2b[(size_t)(c0 + ty + i) * 3072 + r0 + tx] = __float2bfloat16(t[tx][ty + i]);
  }
}

// ---------------------------------------------------------------- bf16 MFMA GEMM (BK templated)
template <int BM, int BN, int BK, int GELU, int BF16OUT, int VOUT = 0>
__global__ __launch_bounds__(256) void gemm_bf16(const bf16* __restrict__ A,
                                                 const bf16* __restrict__ BT,
                                                 const float* __restrict__ bias,
                                                 void* __restrict__ Cout,
                                                 int N, int Kd,
                                                 bf16* __restrict__ vTout = nullptr) {
  constexpr int WM = BM / 2, MF = WM / 16;
  constexpr int WN = BN / 2, FN = WN / 16;
  constexpr int KF = BK / 32;
  constexpr int ROWB = BK * 2;
  constexpr int RPC = 1024 / ROWB;
  constexpr int NCH = BM * BK / 512;
  __shared__ bf16 As[BM * BK];
  __shared__ bf16 Bs[BN * BK];
  const int tid = threadIdx.x, w = tid >> 6, lane = tid & 63;
  int gx = gridDim.x;
  int flat = blockIdx.x + gx * blockIdx.y;
  int cpx = (gx * gridDim.y) >> 3;
  int sw = (flat & 7) * cpx + (flat >> 3);
  const int bn = sw % gx, bm = sw / gx;
  const int wr = w >> 1, wc = w & 1;
  const int c15 = lane & 15, g4 = lane >> 4;
  const int rowInC = lane / (ROWB / 16);
  const int colb = (lane % (ROWB / 16)) * 16;

  f32x4 acc[MF][FN];
  const f32x4 vzero = {0.f, 0.f, 0.f, 0.f};
#pragma unroll
  for (int i = 0; i < MF; ++i)
#pragma unroll
    for (int j = 0; j < FN; ++j) acc[i][j] = vzero;

  const char* Ab = (const char*)A;
  const char* Bb = (const char*)BT;

  for (int k0 = 0; k0 < Kd; k0 += BK) {
#pragma unroll
    for (int i = 0; i < NCH / 4; ++i) {
      int t = w + 4 * i;
      int row = t * RPC + rowInC;
      gload16(Ab + ((size_t)(bm * BM + row) * Kd + k0) * 2 + (colb ^ ((row & 7) << 4)),
              (char*)As + t * 1024);
    }
#pragma unroll
    for (int i = 0; i < (BN * BK / 512) / 4; ++i) {
      int t = w + 4 * i;
      int row = t * RPC + rowInC;
      gload16(Bb + ((size_t)(bn * BN + row) * Kd + k0) * 2 + (colb ^ ((row & 7) << 4)),
              (char*)Bs + t * 1024);
    }
    __syncthreads();
    if constexpr (KF <= 2) {
      bf16x8 af[MF][KF], bfr[FN][KF];
#pragma unroll
      for (int kf = 0; kf < KF; ++kf) {
        int kbyte = kf * 64 + g4 * 16;
#pragma unroll
        for (int mf = 0; mf < MF; ++mf) {
          int row = wr * WM + mf * 16 + c15;
          af[mf][kf] = *(const bf16x8*)((const char*)As + row * ROWB + (kbyte ^ ((row & 7) << 4)));
        }
#pragma unroll
        for (int fn = 0; fn < FN; ++fn) {
          int row = wc * WN + fn * 16 + c15;
          bfr[fn][kf] = *(const bf16x8*)((const char*)Bs + row * ROWB + (kbyte ^ ((row & 7) << 4)));
        }
      }
      __builtin_amdgcn_s_setprio(1);
#pragma unroll
      for (int mf = 0; mf < MF; ++mf)
#pragma unroll
        for (int fn = 0; fn < FN; ++fn)
#pragma unroll
          for (int kf = 0; kf < KF; ++kf)
            acc[mf][fn] = __builtin_amdgcn_mfma_f32_16x16x32_bf16(af[mf][kf], bfr[fn][kf], acc[mf][fn], 0, 0, 0);
      __builtin_amdgcn_s_setprio(0);
    } else {
#pragma unroll
      for (int kf = 0; kf < KF; ++kf) {
        int kbyte = kf * 64 + g4 * 16;
        bf16x8 af[MF], bfr[FN];
#pragma unroll
        for (int mf = 0; mf < MF; ++mf) {
          int row = wr * WM + mf * 16 + c15;
          af[mf] = *(const bf16x8*)((const char*)As + row * ROWB + (kbyte ^ ((row & 7) << 4)));
        }
#pragma unroll
        for (int fn = 0; fn < FN; ++fn) {
          int row = wc * WN + fn * 16 + c15;
          bfr[fn] = *(const bf16x8*)((const char*)Bs + row * ROWB + (kbyte ^ ((row & 7) << 4)));
        }
        __builtin_amdgcn_s_setprio(1);
#pragma unroll
        for (int mf = 0; mf < MF; ++mf)
#pragma unroll
          for (int fn = 0; fn < FN; ++fn)
            acc[mf][fn] = __builtin_amdgcn_mfma_f32_16x16x32_bf16(af[mf], bfr[fn], acc[mf][fn], 0, 0, 0);
        __builtin_amdgcn_s_setprio(0);
      }
    }
    __syncthreads();
  }
#pragma unroll
  for (int fn = 0; fn < FN; ++fn) {
    int col = bn * BN + wc * WN + fn * 16 + c15;
    float bv = bias[col];
#pragma unroll
    for (int mf = 0; mf < MF; ++mf) {
#pragma unroll
      for (int r = 0; r < 4; ++r) {
        int row = bm * BM + wr * WM + mf * 16 + g4 * 4 + r;
        float vv = acc[mf][fn][r] + bv;
        if (GELU) vv = 0.5f * vv * (1.0f + erff(vv * 0.70710678f));
        if (BF16OUT) {
          if (VOUT && col >= 1536) {
            int hd2 = col - 1536, hh = hd2 >> 6, dd = hd2 & 63;
            int bb = row >> 11, ll = row & 2047;
            vTout[((size_t)((bb * 12 + hh) * 64 + dd) << 11) + ll] = __float2bfloat16(vv);
          } else {
            ((bf16*)Cout)[(size_t)row * N + col] = __float2bfloat16(vv);
          }
        } else {
          ((float*)Cout)[(size_t)row * N + col] = vv;
        }
      }
    }
  }
}

// ---------------------------------------------------------------- flash attention v7
__global__ __launch_bounds__(256) void attn_mfma(const bf16* __restrict__ qkv,
                                                 const bf16* __restrict__ vT,
                                                 bf16* __restrict__ ob) {
  int bid = blockIdx.x + 32 * (blockIdx.y + 12 * blockIdx.z);
  int wgid = (bid & 7) * 96 + (bid >> 3);
  const int q0 = (wgid & 31) * 64;
  int bh = wgid >> 5;
  const int h = bh % 12, b = bh / 12;

  const int tid = threadIdx.x, w = tid >> 6, lane = tid & 63;
  const int c15 = lane & 15, g4 = lane >> 4;
  const int lrow8 = lane >> 3;
  const int cb = (lane & 7) * 16;
  __shared__ bf16 Kl[2][4096];
  __shared__ bf16 Vl[3][4096];
  __shared__ bf16 Pl[4096];

  const f32x4 vzero = {0.f, 0.f, 0.f, 0.f};
  const char* qp = (const char*)qkv + (((size_t)(b * 2048 + q0 + w * 16 + c15)) * 2304 + h * 64) * 2;
  bf16x8 qa0 = *(const bf16x8*)(qp + g4 * 16);
  bf16x8 qa1 = *(const bf16x8*)(qp + 64 + g4 * 16);

  bf16x8 b_one;
#pragma unroll
  for (int i = 0; i < 8; ++i) b_one[i] = (__bf16)1.0f;

  f32x4 o[4], o5;
#pragma unroll
  for (int i = 0; i < 4; ++i) o[i] = vzero;
  o5 = vzero;
  float m = -1e30f;
  const float SC2 = 0.18033688f;
  const float THR = 11.54f;

  const char* kgb = (const char*)qkv + (((size_t)(b * 2048)) * 2304 + 768 + h * 64) * 2;
  const char* vgb = (const char*)vT + ((size_t)((b * 12 + h) * 64) * 2048) * 2;
  char* Plw = (char*)Pl + w * 2048;

  const int rr0 = w * 8 + lrow8;
  const int swz = cb ^ (lrow8 << 4);
  const char* ka0 = kgb + (size_t)rr0 * 4608 + swz;
  const char* ka1 = ka0 + 32 * 4608;
  const char* va0 = vgb + (size_t)rr0 * 4096 + swz;
  const char* va1 = va0 + 32 * 4096;
  char* kd0 = (char*)Kl[0] + w * 1024;
  char* vd0 = (char*)Vl[0] + w * 1024;

#define STAGE_K(kt, bufi)                                                      \
  {                                                                            \
    size_t ko = (size_t)(kt) * 294912;                                         \
    int lo = (bufi) * 8192;                                                    \
    gload16(ka0 + ko, kd0 + lo);                                               \
    gload16(ka1 + ko, kd0 + lo + 4096);                                        \
  }
#define STAGE_V(kt, bufi)                                                      \
  {                                                                            \
    size_t vo = (size_t)(kt) * 128;                                            \
    int lo = (bufi) * 8192;                                                    \
    gload16(va0 + vo, vd0 + lo);                                               \
    gload16(va1 + vo, vd0 + lo + 4096);                                        \
  }

#define DO_QK(SC, kbuf)                                                        \
  {                                                                            \
    const char* Kc = (const char*)Kl[kbuf];                                    \
    __builtin_amdgcn_s_setprio(1);                                             \
    _Pragma("unroll")                                                          \
    for (int fn = 0; fn < 4; ++fn) {                                           \
      int key = fn * 16 + c15;                                                 \
      const char* kr = Kc + key * 128;                                         \
      int swk = (key & 7) << 4;                                                \
      bf16x8 kb0 = *(const bf16x8*)(kr + ((g4 * 16) ^ swk));                   \
      bf16x8 kb1 = *(const bf16x8*)(kr + ((64 + g4 * 16) ^ swk));              \
      f32x4 s = __builtin_amdgcn_mfma_f32_16x16x32_bf16(kb0, qa0, vzero, 0, 0, 0); \
      s = __builtin_amdgcn_mfma_f32_16x16x32_bf16(kb1, qa1, s, 0, 0, 0);       \
      SC[fn] = s;                                                              \
    }                                                                          \
    __builtin_amdgcn_s_setprio(0);                                             \
  }

#define DO_SMPV(SC, vbuf)                                                      \
  {                                                                            \
    float pm = fmaxf(                                                          \
        fmaxf(fmaxf(fmaxf(SC[0][0], SC[0][1]), fmaxf(SC[0][2], SC[0][3])),     \
              fmaxf(fmaxf(SC[1][0], SC[1][1]), fmaxf(SC[1][2], SC[1][3]))),    \
        fmaxf(fmaxf(fmaxf(SC[2][0], SC[2][1]), fmaxf(SC[2][2], SC[2][3])),     \
              fmaxf(fmaxf(SC[3][0], SC[3][1]), fmaxf(SC[3][2], SC[3][3]))));   \
    int ok = (pm * SC2 <= m + THR) ? 1 : 0;                                    \
    if (!__all(ok)) {                                                          \
      float tm = pm;                                                           \
      tm = fmaxf(tm, __shfl_xor(tm, 16));                                      \
      tm = fmaxf(tm, __shfl_xor(tm, 32));                                      \
      float mn = fmaxf(m, tm * SC2);                                           \
      float alpha = exp2f(m - mn);                                             \
      m = mn;                                                                  \
      _Pragma("unroll")                                                        \
      for (int r = 0; r < 4; ++r) {                                            \
        float ar = __shfl(alpha, g4 * 4 + r);                                  \
        o[0][r] *= ar; o[1][r] *= ar; o[2][r] *= ar; o[3][r] *= ar;            \
        o5[r] *= ar;                                                           \
      }                                                                        \
    }                                                                          \
    {                                                                          \
      char* prow = Plw + c15 * 128;                                            \
      int swp = (c15 & 7) << 4;                                                \
      _Pragma("unroll")                                                        \
      for (int fn = 0; fn < 4; ++fn) {                                         \
        union { bf16 hh[4]; uint2 u; } pk;                                     \
        _Pragma("unroll")                                                      \
        for (int r = 0; r < 4; ++r)                                            \
          pk.hh[r] = __float2bfloat16(exp2f(fmaf(SC[fn][r], SC2, -m)));        \
        *(uint2*)(prow + ((fn * 32 + g4 * 8) ^ swp)) = pk.u;                   \
      }                                                                        \
    }                                                                          \
    {                                                                          \
      const char* pr = Plw + c15 * 128;                                        \
      int swp2 = (c15 & 7) << 4;                                               \
      bf16x8 pa0 = *(const bf16x8*)(pr + ((g4 * 16) ^ swp2));                  \
      bf16x8 pa1 = *(const bf16x8*)(pr + ((64 + g4 * 16) ^ swp2));             \
      const char* Vc = (const char*)Vl[vbuf];                                  \
      __builtin_amdgcn_s_setprio(1);                                           \
      _Pragma("unroll")                                                        \
      for (int fh = 0; fh < 4; ++fh) {                                         \
        int hd = fh * 16 + c15;                                                \
        const char* vr = Vc + hd * 128;                                        \
        int swv = (hd & 7) << 4;                                               \
        bf16x8 vb0 = *(const bf16x8*)(vr + ((g4 * 16) ^ swv));                 \
        bf16x8 vb1 = *(const bf16x8*)(vr + ((64 + g4 * 16) ^ swv));            \
        o[fh] = __builtin_amdgcn_mfma_f32_16x16x32_bf16(pa0, vb0, o[fh], 0, 0, 0); \
        o[fh] = __builtin_amdgcn_mfma_f32_16x16x32_bf16(pa1, vb1, o[fh], 0, 0, 0); \
      }                                                                        \
      o5 = __builtin_amdgcn_mfma_f32_16x16x32_bf16(pa0, b_one, o5, 0, 0, 0);   \
      o5 = __builtin_amdgcn_mfma_f32_16x16x32_bf16(pa1, b_one, o5, 0, 0, 0);   \
      __builtin_amdgcn_s_setprio(0);                                           \
    }                                                                          \
  }

  STAGE_K(0, 0); STAGE_K(1, 1); STAGE_V(0, 0); STAGE_V(1, 1);
  __syncthreads();

  f32x4 scA[4], scB[4];
  DO_QK(scA, 0);

#define ITER(kt, SCUR, SNXT)                                                   \
  {                                                                            \
    if ((kt) + 2 < 32) {                                                       \
      STAGE_K((kt) + 2, (kt) & 1);                                             \
      STAGE_V((kt) + 2, ((kt) + 2) % 3);                                       \
    }                                                                          \
    if ((kt) + 1 < 32) DO_QK(SNXT, ((kt) + 1) & 1);                            \
    DO_SMPV(SCUR, (kt) % 3);                                                   \
    __syncthreads();                                                           \
  }

#pragma unroll 2
  for (int kt2 = 0; kt2 < 32; kt2 += 2) {
    ITER(kt2, scA, scB);
    ITER(kt2 + 1, scB, scA);
  }
#undef ITER
#undef DO_SMPV
#undef DO_QK
#undef STAGE_K
#undef STAGE_V

#pragma unroll
  for (int r = 0; r < 4; ++r) {
    float inv = 1.0f / o5[r];
    size_t row = (size_t)(b * 2048 + q0 + w * 16 + g4 * 4 + r);
#pragma unroll
    for (int fh = 0; fh < 4; ++fh)
      ob[row * 768 + h * 64 + fh * 16 + c15] = __float2bfloat16(o[fh][r] * inv);
  }
}

// ----------------------------------------------------------------
extern "C" void kernel_launch(void* const* d_in, const int* in_sizes, int n_in,
                              void* d_out, int out_size, void* d_ws, size_t ws_size,
                              hipStream_t stream) {
  const float* x      = (const float*)d_in[0];
  const float* pcw    = (const float*)d_in[1];
  const float* pcb    = (const float*)d_in[2];
  const float* ln0_g  = (const float*)d_in[3];
  const float* ln0_b  = (const float*)d_in[4];
  const float* Wq     = (const float*)d_in[5];
  const float* bq     = (const float*)d_in[6];
  const float* Wk     = (const float*)d_in[7];
  const float* bk     = (const float*)d_in[8];
  const float* Wv     = (const float*)d_in[9];
  const float* bv     = (const float*)d_in[10];
  const float* Wo     = (const float*)d_in[11];
  const float* bo     = (const float*)d_in[12];
  const float* ln1_g  = (const float*)d_in[13];
  const float* ln1_b  = (const float*)d_in[14];
  const float* W1     = (const float*)d_in[15];
  const float* b1     = (const float*)d_in[16];
  const float* W2     = (const float*)d_in[17];
  const float* b2     = (const float*)d_in[18];
  const float* ln2_g  = (const float*)d_in[19];
  const float* ln2_b  = (const float*)d_in[20];

  const size_t MDB = (size_t)M_TOK * D_ * 4;
  char* W = (char*)d_ws;
  float* tmp  = (float*)(W + MDB);
  char*  big  = W + 2 * MDB;
  bf16*  qkv  = (bf16*)big;
  bf16*  ff   = (bf16*)big;
  bf16*  wT2  = (bf16*)big;
  bf16*  tmp_bf = (bf16*)W;
  char* p = W + 2 * MDB + 25165824;
  bf16* h_bf  = (bf16*)p; p += (size_t)M_TOK * D_ * 2;
  bf16* obuf  = (bf16*)p; p += (size_t)M_TOK * D_ * 2;
  bf16* vT    = (bf16*)p; p += (size_t)M_TOK * D_ * 2;
  bf16* wqkvb = (bf16*)p; p += (size_t)2304 * 768 * 2;
  bf16* wob   = (bf16*)p; p += (size_t)768 * 768 * 2;
  bf16* w1b   = (bf16*)p; p += (size_t)3072 * 768 * 2;
  bf16* w2b   = (bf16*)p; p += (size_t)768 * 3072 * 2;
  float* bqkv = (float*)p;

  convw_kernel<<<24576, 256, 0, stream>>>(pcw, wT2);
  conv_mfma<<<512, 256, 0, stream>>>(x, wT2, pcb, tmp);
  ln_kernel<<<M_TOK / 4, 256, 0, stream>>>(tmp, ln0_g, ln0_b, h_bf);

  for (int l = 0; l < NL_; ++l) {
    prep_weights<<<6921, 256, 0, stream>>>(Wq, Wk, Wv, Wo, W1, W2, bq, bk, bv,
                                           wqkvb, wob, w1b, w2b, bqkv, l);

    gemm_bf16<128, 128, 64, 0, 1, 1><<<dim3(18, 32), 256, 0, stream>>>(h_bf, wqkvb, bqkv, qkv, 2304, 768, vT);
    attn_mfma<<<dim3(32, 12, 2), 256, 0, stream>>>(qkv, vT, obuf);
    gemm_bf16<64, 64, 128, 0, 1><<<dim3(12, 64), 256, 0, stream>>>(obuf, wob, bo + (size_t)l * D_, tmp_bf, 768, 768);
    ln_bf<0><<<M_TOK / 4, 256, 0, stream>>>(tmp_bf, h_bf, ln1_g + (size_t)l * D_, ln1_b + (size_t)l * D_, h_bf, nullptr);
    gemm_bf16<128, 128, 64, 1, 1><<<dim3(24, 32), 256, 0, stream>>>(h_bf, w1b, b1 + (size_t)l * F_, ff, 3072, 768);
    gemm_bf16<64, 64, 128, 0, 1><<<dim3(12, 64), 256, 0, stream>>>(ff, w2b, b2 + (size_t)l * D_, tmp_bf, 768, 3072);
    if (l == NL_ - 1)
      ln_bf<1><<<M_TOK / 4, 256, 0, stream>>>(tmp_bf, h_bf, ln2_g + (size_t)l * D_, ln2_b + (size_t)l * D_, h_bf, (float*)d_out);
    else
      ln_bf<0><<<M_TOK / 4, 256, 0, stream>>>(tmp_bf, h_bf, ln2_g + (size_t)l * D_, ln2_b + (size_t)l * D_, h_bf, nullptr);
  }
}

// Round 20
// 2234.610 us; speedup vs baseline: 1.0929x; 1.0148x over previous
//
#include <hip/hip_runtime.h>
#include <hip/hip_bf16.h>
#include <stdint.h>

#define B_ 2
#define L_ 2048
#define D_ 768
#define H_ 12
#define F_ 3072
#define NL_ 12
#define K_ 128
#define G_ 16
#define HD_ 64
#define CPG_ 48
#define M_TOK (B_*L_)
#define SCALE_ 0.125f

typedef __hip_bfloat16 bf16;
typedef __bf16 bf16x8 __attribute__((ext_vector_type(8)));
typedef float f32x4 __attribute__((ext_vector_type(4)));

__device__ __forceinline__ void gload16(const void* g, void* l) {
  __builtin_amdgcn_global_load_lds((const __attribute__((address_space(1))) void*)g,
                                   (__attribute__((address_space(3))) void*)l, 16, 0, 0);
}

// ---------------------------------------------------------------- conv weight pre-transpose
__global__ __launch_bounds__(256) void convw_kernel(const float* __restrict__ w,
                                                    bf16* __restrict__ wT2) {
  int idx = blockIdx.x * 256 + threadIdx.x;
  int ci = idx & 63;
  int row = idx >> 6;
  int d = row % 48;
  int t2 = row / 48;
  int kk = t2 & 127;
  int g = t2 >> 7;
  float v = (ci < 48) ? w[(((size_t)(g * 48 + d) * 48) + ci) * 128 + kk] : 0.f;
  wT2[idx] = __float2bfloat16(v);
}

// ---------------------------------------------------------------- conv via MFMA (dbuf weights)
__global__ __launch_bounds__(256) void conv_mfma(const float* __restrict__ x,
                                                 const bf16* __restrict__ wT2,
                                                 const float* __restrict__ bias,
                                                 float* __restrict__ out) {
  int flat = blockIdx.x;
  int wgid = (flat & 7) * 64 + (flat >> 3);
  const int g = wgid >> 5;
  int rem = wgid & 31;
  const int l0 = (rem & 15) * 128;
  const int b = rem >> 4;

  const int tid = threadIdx.x, w = tid >> 6, lane = tid & 63;
  const int c15 = lane & 15, g4 = lane >> 4;
  __shared__ __align__(16) bf16 win[256 * 64];
  __shared__ __align__(16) bf16 Wl[2][2 * 48 * 64];

  {
    int lg = l0 - 64 + tid;
    char* dst = (char*)win + tid * 128;
    int swr = (tid & 7) << 4;
    uint4 z4 = {0u, 0u, 0u, 0u};
    if ((unsigned)lg < 2048u) {
      const float* srow = x + ((size_t)(b * 2048 + lg) * 768 + g * 48);
#pragma unroll
      for (int c = 0; c < 6; ++c) {
        float4 v0 = *(const float4*)(srow + c * 8);
        float4 v1 = *(const float4*)(srow + c * 8 + 4);
        union { bf16 h[8]; uint4 u; } uu;
        uu.h[0] = __float2bfloat16(v0.x); uu.h[1] = __float2bfloat16(v0.y);
        uu.h[2] = __float2bfloat16(v0.z); uu.h[3] = __float2bfloat16(v0.w);
        uu.h[4] = __float2bfloat16(v1.x); uu.h[5] = __float2bfloat16(v1.y);
        uu.h[6] = __float2bfloat16(v1.z); uu.h[7] = __float2bfloat16(v1.w);
        *(uint4*)(dst + ((c * 16) ^ swr)) = uu.u;
      }
    } else {
#pragma unroll
      for (int c = 0; c < 6; ++c) *(uint4*)(dst + ((c * 16) ^ swr)) = z4;
    }
    *(uint4*)(dst + (96 ^ swr)) = z4;
    *(uint4*)(dst + (112 ^ swr)) = z4;
  }

  const char* wbase = (const char*)wT2 + (size_t)g * 128 * 48 * 128;
  const int coff = w * 3072;
#define STAGEW(kp, bufi)                                                                   \
  {                                                                                        \
    _Pragma("unroll")                                                                      \
    for (int i = 0; i < 3; ++i) {                                                          \
      int c = coff + i * 1024 + (lane << 4);                                               \
      int row96 = c >> 7;                                                                  \
      int s = row96 / 48;                                                                  \
      int d = row96 - s * 48;                                                              \
      int cb2 = c & 127;                                                                   \
      gload16(wbase + ((size_t)((2 * (kp) + s) * 48 + d)) * 128 + (cb2 ^ ((d & 7) << 4)),  \
              (char*)Wl[bufi] + coff + i * 1024);                                          \
    }                                                                                      \
  }

  f32x4 acc[2][3];
  const f32x4 vzero = {0.f, 0.f, 0.f, 0.f};
#pragma unroll
  for (int i = 0; i < 2; ++i)
#pragma unroll
    for (int j = 0; j < 3; ++j) acc[i][j] = vzero;

  STAGEW(0, 0);
  __syncthreads();

  for (int kp = 0; kp < 64; ++kp) {
    int cur = kp & 1;
    if (kp + 1 < 64) STAGEW(kp + 1, cur ^ 1);
    const char* Wc = (const char*)Wl[cur];
#pragma unroll
    for (int s = 0; s < 2; ++s) {
      int kk = 2 * kp + s;
#pragma unroll
      for (int cb = 0; cb < 2; ++cb) {
        int a0r = w * 16 + c15 + kk;
        int a1r = 64 + a0r;
        bf16x8 a0 = *(const bf16x8*)((const char*)win + a0r * 128 + ((cb * 64 + g4 * 16) ^ ((a0r & 7) << 4)));
        bf16x8 a1 = *(const bf16x8*)((const char*)win + a1r * 128 + ((cb * 64 + g4 * 16) ^ ((a1r & 7) << 4)));
#pragma unroll
        for (int ct = 0; ct < 3; ++ct) {
          int d = ct * 16 + c15;
          bf16x8 bfrag = *(const bf16x8*)(Wc + s * 6144 + d * 128 +
                                          ((cb * 64 + g4 * 16) ^ ((d & 7) << 4)));
          acc[0][ct] = __builtin_amdgcn_mfma_f32_16x16x32_bf16(a0, bfrag, acc[0][ct], 0, 0, 0);
          acc[1][ct] = __builtin_amdgcn_mfma_f32_16x16x32_bf16(a1, bfrag, acc[1][ct], 0, 0, 0);
        }
      }
    }
    __syncthreads();
  }
#undef STAGEW

#pragma unroll
  for (int ls = 0; ls < 2; ++ls)
#pragma unroll
    for (int ct = 0; ct < 3; ++ct) {
      int dg = g * 48 + ct * 16 + c15;
      float bv = bias[dg];
#pragma unroll
      for (int r = 0; r < 4; ++r) {
        int l = l0 + ls * 64 + w * 16 + g4 * 4 + r;
        size_t idx = (size_t)(b * 2048 + l) * 768 + dg;
        float vv = acc[ls][ct][r] + bv;
        vv = 0.5f * vv * (1.0f + erff(vv * 0.70710678f));
        out[idx] = x[idx] + vv;
      }
    }
}

// ---------------------------------------------------------------- layernorm f32-in (ln0 only)
__global__ __launch_bounds__(256) void ln_kernel(const float* __restrict__ a,
                                                 const float* __restrict__ g,
                                                 const float* __restrict__ be,
                                                 bf16* __restrict__ outb) {
  int w = threadIdx.x >> 6, lane = threadIdx.x & 63;
  size_t row = (size_t)blockIdx.x * 4 + w;
  const float* ar = a + row * 768;
  float4 v[3];
  float s = 0.f;
#pragma unroll
  for (int i = 0; i < 3; ++i) {
    int c = lane * 4 + i * 256;
    float4 vv = *(const float4*)(ar + c);
    v[i] = vv;
    s += vv.x + vv.y + vv.z + vv.w;
  }
#pragma unroll
  for (int st = 1; st < 64; st <<= 1) s += __shfl_xor(s, st);
  float mean = s * (1.0f / 768.0f);
  float s2 = 0.f;
#pragma unroll
  for (int i = 0; i < 3; ++i) {
    float dx = v[i].x - mean, dy = v[i].y - mean, dz = v[i].z - mean, dw = v[i].w - mean;
    s2 += dx * dx + dy * dy + dz * dz + dw * dw;
  }
#pragma unroll
  for (int st = 1; st < 64; st <<= 1) s2 += __shfl_xor(s2, st);
  float rstd = rsqrtf(s2 * (1.0f / 768.0f) + 1e-5f);
#pragma unroll
  for (int i = 0; i < 3; ++i) {
    int c = lane * 4 + i * 256;
    float4 gv = *(const float4*)(g + c);
    float4 bv = *(const float4*)(be + c);
    union { bf16 h[4]; uint2 u; } pk;
    pk.h[0] = __float2bfloat16((v[i].x - mean) * rstd * gv.x + bv.x);
    pk.h[1] = __float2bfloat16((v[i].y - mean) * rstd * gv.y + bv.y);
    pk.h[2] = __float2bfloat16((v[i].z - mean) * rstd * gv.z + bv.z);
    pk.h[3] = __float2bfloat16((v[i].w - mean) * rstd * gv.w + bv.w);
    *(uint2*)(outb + row * 768 + c) = pk.u;
  }
}

// ---------------------------------------------------------------- layernorm bf16-in + bf16 residual
template <int F32OUT>
__global__ __launch_bounds__(256) void ln_bf(const bf16* __restrict__ a,
                                             const bf16* __restrict__ r,
                                             const float* __restrict__ g,
                                             const float* __restrict__ be,
                                             bf16* __restrict__ outb,
                                             float* __restrict__ outf) {
  int w = threadIdx.x >> 6, lane = threadIdx.x & 63;
  size_t row = (size_t)blockIdx.x * 4 + w;
  const bf16* ar = a + row * 768;
  const bf16* rr = r + row * 768;
  float v[3][4];
  float s = 0.f;
#pragma unroll
  for (int i = 0; i < 3; ++i) {
    int c = lane * 4 + i * 256;
    union { uint2 u; uint16_t h[4]; } ua, urr;
    ua.u = *(const uint2*)(ar + c);
    urr.u = *(const uint2*)(rr + c);
#pragma unroll
    for (int j = 0; j < 4; ++j) {
      float x = __uint_as_float((uint32_t)ua.h[j] << 16) +
                __uint_as_float((uint32_t)urr.h[j] << 16);
      v[i][j] = x; s += x;
    }
  }
#pragma unroll
  for (int st = 1; st < 64; st <<= 1) s += __shfl_xor(s, st);
  float mean = s * (1.0f / 768.0f);
  float s2 = 0.f;
#pragma unroll
  for (int i = 0; i < 3; ++i)
#pragma unroll
    for (int j = 0; j < 4; ++j) {
      float d2 = v[i][j] - mean;
      s2 += d2 * d2;
    }
#pragma unroll
  for (int st = 1; st < 64; st <<= 1) s2 += __shfl_xor(s2, st);
  float rstd = rsqrtf(s2 * (1.0f / 768.0f) + 1e-5f);
#pragma unroll
  for (int i = 0; i < 3; ++i) {
    int c = lane * 4 + i * 256;
    float4 gv = *(const float4*)(g + c);
    float4 bv = *(const float4*)(be + c);
    float o0 = (v[i][0] - mean) * rstd * gv.x + bv.x;
    float o1 = (v[i][1] - mean) * rstd * gv.y + bv.y;
    float o2 = (v[i][2] - mean) * rstd * gv.z + bv.z;
    float o3 = (v[i][3] - mean) * rstd * gv.w + bv.w;
    union { bf16 h[4]; uint2 u; } pk;
    pk.h[0] = __float2bfloat16(o0); pk.h[1] = __float2bfloat16(o1);
    pk.h[2] = __float2bfloat16(o2); pk.h[3] = __float2bfloat16(o3);
    *(uint2*)(outb + row * 768 + c) = pk.u;
    if (F32OUT) {
      float4 of = {o0, o1, o2, o3};
      *(float4*)(outf + row * 768 + c) = of;
    }
  }
}

// ---------------------------------------------------------------- weight prep (per-layer)
__global__ __launch_bounds__(256) void prep_weights(const float* __restrict__ WqB,
                                                    const float* __restrict__ WkB,
                                                    const float* __restrict__ WvB,
                                                    const float* __restrict__ WoB,
                                                    const float* __restrict__ W1B,
                                                    const float* __restrict__ W2B,
                                                    const float* __restrict__ bqB,
                                                    const float* __restrict__ bkB,
                                                    const float* __restrict__ bvB,
                                                    bf16* __restrict__ wqkvb,
                                                    bf16* __restrict__ wob,
                                                    bf16* __restrict__ w1b,
                                                    bf16* __restrict__ w2b,
                                                    float* __restrict__ bqkv,
                                                    int l) {
  __shared__ float t[32][33];
  int tid = threadIdx.x;
  int tx = tid & 31, ty = tid >> 5;
  const float* wq = WqB + (size_t)l * 768 * 768;
  const float* wk = WkB + (size_t)l * 768 * 768;
  const float* wv = WvB + (size_t)l * 768 * 768;
  const float* wo = WoB + (size_t)l * 768 * 768;
  const float* w1 = W1B + (size_t)l * 768 * 3072;
  const float* w2 = W2B + (size_t)l * 3072 * 768;

  int blk = blockIdx.x;
  if (blk >= 6912) {
    int i = (blk - 6912) * 256 + tid;
    if (i < 2304)
      bqkv[i] = (i < 768) ? bqB[(size_t)l * 768 + i]
              : (i < 1536) ? bkB[(size_t)l * 768 + i - 768]
                           : bvB[(size_t)l * 768 + i - 1536];
    return;
  }
  if (blk < 1728) {
    int n0 = (blk % 72) * 32, k0 = (blk / 72) * 32;
    const float* src = (n0 < 768) ? wq : (n0 < 1536) ? wk : wv;
    int nn = (n0 >= 1536) ? (n0 - 1536) : (n0 >= 768 ? n0 - 768 : n0);
#pragma unroll
    for (int i = 0; i < 32; i += 8) t[ty + i][tx] = src[(size_t)(k0 + ty + i) * 768 + nn + tx];
    __syncthreads();
#pragma unroll
    for (int i = 0; i < 32; i += 8)
      wqkvb[(size_t)(n0 + ty + i) * 768 + k0 + tx] = __float2bfloat16(t[tx][ty + i]);
    return;
  }
  blk -= 1728;
  if (blk < 576) {
    int c0 = (blk % 24) * 32, r0 = (blk / 24) * 32;
#pragma unroll
    for (int i = 0; i < 32; i += 8) t[ty + i][tx] = wo[(size_t)(r0 + ty + i) * 768 + c0 + tx];
    __syncthreads();
#pragma unroll
    for (int i = 0; i < 32; i += 8)
      wob[(size_t)(c0 + ty + i) * 768 + r0 + tx] = __float2bfloat16(t[tx][ty + i]);
    return;
  }
  blk -= 576;
  if (blk < 2304) {
    int c0 = (blk % 96) * 32, r0 = (blk / 96) * 32;
#pragma unroll
    for (int i = 0; i < 32; i += 8) t[ty + i][tx] = w1[(size_t)(r0 + ty + i) * 3072 + c0 + tx];
    __syncthreads();
#pragma unroll
    for (int i = 0; i < 32; i += 8)
      w1b[(size_t)(c0 + ty + i) * 768 + r0 + tx] = __float2bfloat16(t[tx][ty + i]);
    return;
  }
  blk -= 2304;
  {
    int c0 = (blk % 24) * 32, r0 = (blk / 24) * 32;
#pragma unroll
    for (int i = 0; i < 32; i += 8) t[ty + i][tx] = w2[(size_t)(r0 + ty + i) * 768 + c0 + tx];
    __syncthreads();
#pragma unroll
    for (int i = 0; i < 32; i += 8)
      w2b[(size_t)(c0 + ty + i) * 3072 + r0 + tx] = __float2bfloat16(t[tx][ty + i]);
  }
}

// ---------------------------------------------------------------- bf16 MFMA GEMM (BK templated, full fragment preload)
template <int BM, int BN, int BK, int GELU, int BF16OUT, int VOUT = 0>
__global__ __launch_bounds__(256) void gemm_bf16(const bf16* __restrict__ A,
                                                 const bf16* __restrict__ BT,
                                                 const float* __restrict__ bias,
                                                 void* __restrict__ Cout,
                                                 int N, int Kd,
                                                 bf16* __restrict__ vTout = nullptr) {
  constexpr int WM = BM / 2, MF = WM / 16;
  constexpr int WN = BN / 2, FN = WN / 16;
  constexpr int KF = BK / 32;
  constexpr int ROWB = BK * 2;
  constexpr int RPC = 1024 / ROWB;
  constexpr int NCH = BM * BK / 512;
  __shared__ bf16 As[BM * BK];
  __shared__ bf16 Bs[BN * BK];
  const int tid = threadIdx.x, w = tid >> 6, lane = tid & 63;
  int gx = gridDim.x;
  int flat = blockIdx.x + gx * blockIdx.y;
  int cpx = (gx * gridDim.y) >> 3;
  int sw = (flat & 7) * cpx + (flat >> 3);
  const int bn = sw % gx, bm = sw / gx;
  const int wr = w >> 1, wc = w & 1;
  const int c15 = lane & 15, g4 = lane >> 4;
  const int rowInC = lane / (ROWB / 16);
  const int colb = (lane % (ROWB / 16)) * 16;

  f32x4 acc[MF][FN];
  const f32x4 vzero = {0.f, 0.f, 0.f, 0.f};
#pragma unroll
  for (int i = 0; i < MF; ++i)
#pragma unroll
    for (int j = 0; j < FN; ++j) acc[i][j] = vzero;

  const char* Ab = (const char*)A;
  const char* Bb = (const char*)BT;

  for (int k0 = 0; k0 < Kd; k0 += BK) {
#pragma unroll
    for (int i = 0; i < NCH / 4; ++i) {
      int t = w + 4 * i;
      int row = t * RPC + rowInC;
      gload16(Ab + ((size_t)(bm * BM + row) * Kd + k0) * 2 + (colb ^ ((row & 7) << 4)),
              (char*)As + t * 1024);
    }
#pragma unroll
    for (int i = 0; i < (BN * BK / 512) / 4; ++i) {
      int t = w + 4 * i;
      int row = t * RPC + rowInC;
      gload16(Bb + ((size_t)(bn * BN + row) * Kd + k0) * 2 + (colb ^ ((row & 7) << 4)),
              (char*)Bs + t * 1024);
    }
    __syncthreads();
    bf16x8 af[MF][KF], bfr[FN][KF];
#pragma unroll
    for (int kf = 0; kf < KF; ++kf) {
      int kbyte = kf * 64 + g4 * 16;
#pragma unroll
      for (int mf = 0; mf < MF; ++mf) {
        int row = wr * WM + mf * 16 + c15;
        af[mf][kf] = *(const bf16x8*)((const char*)As + row * ROWB + (kbyte ^ ((row & 7) << 4)));
      }
#pragma unroll
      for (int fn = 0; fn < FN; ++fn) {
        int row = wc * WN + fn * 16 + c15;
        bfr[fn][kf] = *(const bf16x8*)((const char*)Bs + row * ROWB + (kbyte ^ ((row & 7) << 4)));
      }
    }
    __builtin_amdgcn_s_setprio(1);
#pragma unroll
    for (int mf = 0; mf < MF; ++mf)
#pragma unroll
      for (int fn = 0; fn < FN; ++fn)
#pragma unroll
        for (int kf = 0; kf < KF; ++kf)
          acc[mf][fn] = __builtin_amdgcn_mfma_f32_16x16x32_bf16(af[mf][kf], bfr[fn][kf], acc[mf][fn], 0, 0, 0);
    __builtin_amdgcn_s_setprio(0);
    __syncthreads();
  }
#pragma unroll
  for (int fn = 0; fn < FN; ++fn) {
    int col = bn * BN + wc * WN + fn * 16 + c15;
    float bv = bias[col];
#pragma unroll
    for (int mf = 0; mf < MF; ++mf) {
#pragma unroll
      for (int r = 0; r < 4; ++r) {
        int row = bm * BM + wr * WM + mf * 16 + g4 * 4 + r;
        float vv = acc[mf][fn][r] + bv;
        if (GELU) vv = 0.5f * vv * (1.0f + erff(vv * 0.70710678f));
        if (BF16OUT) {
          if (VOUT && col >= 1536) {
            int hd2 = col - 1536, hh = hd2 >> 6, dd = hd2 & 63;
            int bb = row >> 11, ll = row & 2047;
            vTout[((size_t)((bb * 12 + hh) * 64 + dd) << 11) + ll] = __float2bfloat16(vv);
          } else {
            ((bf16*)Cout)[(size_t)row * N + col] = __float2bfloat16(vv);
          }
        } else {
          ((float*)Cout)[(size_t)row * N + col] = vv;
        }
      }
    }
  }
}

// ---------------------------------------------------------------- flash attention v7
__global__ __launch_bounds__(256) void attn_mfma(const bf16* __restrict__ qkv,
                                                 const bf16* __restrict__ vT,
                                                 bf16* __restrict__ ob) {
  int bid = blockIdx.x + 32 * (blockIdx.y + 12 * blockIdx.z);
  int wgid = (bid & 7) * 96 + (bid >> 3);
  const int q0 = (wgid & 31) * 64;
  int bh = wgid >> 5;
  const int h = bh % 12, b = bh / 12;

  const int tid = threadIdx.x, w = tid >> 6, lane = tid & 63;
  const int c15 = lane & 15, g4 = lane >> 4;
  const int lrow8 = lane >> 3;
  const int cb = (lane & 7) * 16;
  __shared__ bf16 Kl[2][4096];
  __shared__ bf16 Vl[3][4096];
  __shared__ bf16 Pl[4096];

  const f32x4 vzero = {0.f, 0.f, 0.f, 0.f};
  const char* qp = (const char*)qkv + (((size_t)(b * 2048 + q0 + w * 16 + c15)) * 2304 + h * 64) * 2;
  bf16x8 qa0 = *(const bf16x8*)(qp + g4 * 16);
  bf16x8 qa1 = *(const bf16x8*)(qp + 64 + g4 * 16);

  bf16x8 b_one;
#pragma unroll
  for (int i = 0; i < 8; ++i) b_one[i] = (__bf16)1.0f;

  f32x4 o[4], o5;
#pragma unroll
  for (int i = 0; i < 4; ++i) o[i] = vzero;
  o5 = vzero;
  float m = -1e30f;
  const float SC2 = 0.18033688f;
  const float THR = 11.54f;

  const char* kgb = (const char*)qkv + (((size_t)(b * 2048)) * 2304 + 768 + h * 64) * 2;
  const char* vgb = (const char*)vT + ((size_t)((b * 12 + h) * 64) * 2048) * 2;
  char* Plw = (char*)Pl + w * 2048;

  const int rr0 = w * 8 + lrow8;
  const int swz = cb ^ (lrow8 << 4);
  const char* ka0 = kgb + (size_t)rr0 * 4608 + swz;
  const char* ka1 = ka0 + 32 * 4608;
  const char* va0 = vgb + (size_t)rr0 * 4096 + swz;
  const char* va1 = va0 + 32 * 4096;
  char* kd0 = (char*)Kl[0] + w * 1024;
  char* vd0 = (char*)Vl[0] + w * 1024;

#define STAGE_K(kt, bufi)                                                      \
  {                                                                            \
    size_t ko = (size_t)(kt) * 294912;                                         \
    int lo = (bufi) * 8192;                                                    \
    gload16(ka0 + ko, kd0 + lo);                                               \
    gload16(ka1 + ko, kd0 + lo + 4096);                                        \
  }
#define STAGE_V(kt, bufi)                                                      \
  {                                                                            \
    size_t vo = (size_t)(kt) * 128;                                            \
    int lo = (bufi) * 8192;                                                    \
    gload16(va0 + vo, vd0 + lo);                                               \
    gload16(va1 + vo, vd0 + lo + 4096);                                        \
  }

#define DO_QK(SC, kbuf)                                                        \
  {                                                                            \
    const char* Kc = (const char*)Kl[kbuf];                                    \
    __builtin_amdgcn_s_setprio(1);                                             \
    _Pragma("unroll")                                                          \
    for (int fn = 0; fn < 4; ++fn) {                                           \
      int key = fn * 16 + c15;                                                 \
      const char* kr = Kc + key * 128;                                         \
      int swk = (key & 7) << 4;                                                \
      bf16x8 kb0 = *(const bf16x8*)(kr + ((g4 * 16) ^ swk));                   \
      bf16x8 kb1 = *(const bf16x8*)(kr + ((64 + g4 * 16) ^ swk));              \
      f32x4 s = __builtin_amdgcn_mfma_f32_16x16x32_bf16(kb0, qa0, vzero, 0, 0, 0); \
      s = __builtin_amdgcn_mfma_f32_16x16x32_bf16(kb1, qa1, s, 0, 0, 0);       \
      SC[fn] = s;                                                              \
    }                                                                          \
    __builtin_amdgcn_s_setprio(0);                                             \
  }

#define DO_SMPV(SC, vbuf)                                                      \
  {                                                                            \
    float pm = fmaxf(                                                          \
        fmaxf(fmaxf(fmaxf(SC[0][0], SC[0][1]), fmaxf(SC[0][2], SC[0][3])),     \
              fmaxf(fmaxf(SC[1][0], SC[1][1]), fmaxf(SC[1][2], SC[1][3]))),    \
        fmaxf(fmaxf(fmaxf(SC[2][0], SC[2][1]), fmaxf(SC[2][2], SC[2][3])),     \
              fmaxf(fmaxf(SC[3][0], SC[3][1]), fmaxf(SC[3][2], SC[3][3]))));   \
    int ok = (pm * SC2 <= m + THR) ? 1 : 0;                                    \
    if (!__all(ok)) {                                                          \
      float tm = pm;                                                           \
      tm = fmaxf(tm, __shfl_xor(tm, 16));                                      \
      tm = fmaxf(tm, __shfl_xor(tm, 32));                                      \
      float mn = fmaxf(m, tm * SC2);                                           \
      float alpha = exp2f(m - mn);                                             \
      m = mn;                                                                  \
      _Pragma("unroll")                                                        \
      for (int r = 0; r < 4; ++r) {                                            \
        float ar = __shfl(alpha, g4 * 4 + r);                                  \
        o[0][r] *= ar; o[1][r] *= ar; o[2][r] *= ar; o[3][r] *= ar;            \
        o5[r] *= ar;                                                           \
      }                                                                        \
    }                                                                          \
    {                                                                          \
      char* prow = Plw + c15 * 128;                                            \
      int swp = (c15 & 7) << 4;                                                \
      _Pragma("unroll")                                                        \
      for (int fn = 0; fn < 4; ++fn) {                                         \
        union { bf16 hh[4]; uint2 u; } pk;                                     \
        _Pragma("unroll")                                                      \
        for (int r = 0; r < 4; ++r)                                            \
          pk.hh[r] = __float2bfloat16(exp2f(fmaf(SC[fn][r], SC2, -m)));        \
        *(uint2*)(prow + ((fn * 32 + g4 * 8) ^ swp)) = pk.u;                   \
      }                                                                        \
    }                                                                          \
    {                                                                          \
      const char* pr = Plw + c15 * 128;                                        \
      int swp2 = (c15 & 7) << 4;                                               \
      bf16x8 pa0 = *(const bf16x8*)(pr + ((g4 * 16) ^ swp2));                  \
      bf16x8 pa1 = *(const bf16x8*)(pr + ((64 + g4 * 16) ^ swp2));             \
      const char* Vc = (const char*)Vl[vbuf];                                  \
      __builtin_amdgcn_s_setprio(1);                                           \
      _Pragma("unroll")                                                        \
      for (int fh = 0; fh < 4; ++fh) {                                         \
        int hd = fh * 16 + c15;                                                \
        const char* vr = Vc + hd * 128;                                        \
        int swv = (hd & 7) << 4;                                               \
        bf16x8 vb0 = *(const bf16x8*)(vr + ((g4 * 16) ^ swv));                 \
        bf16x8 vb1 = *(const bf16x8*)(vr + ((64 + g4 * 16) ^ swv));            \
        o[fh] = __builtin_amdgcn_mfma_f32_16x16x32_bf16(pa0, vb0, o[fh], 0, 0, 0); \
        o[fh] = __builtin_amdgcn_mfma_f32_16x16x32_bf16(pa1, vb1, o[fh], 0, 0, 0); \
      }                                                                        \
      o5 = __builtin_amdgcn_mfma_f32_16x16x32_bf16(pa0, b_one, o5, 0, 0, 0);   \
      o5 = __builtin_amdgcn_mfma_f32_16x16x32_bf16(pa1, b_one, o5, 0, 0, 0);   \
      __builtin_amdgcn_s_setprio(0);                                           \
    }                                                                          \
  }

  STAGE_K(0, 0); STAGE_K(1, 1); STAGE_V(0, 0); STAGE_V(1, 1);
  __syncthreads();

  f32x4 scA[4], scB[4];
  DO_QK(scA, 0);

#define ITER(kt, SCUR, SNXT)                                                   \
  {                                                                            \
    if ((kt) + 2 < 32) {                                                       \
      STAGE_K((kt) + 2, (kt) & 1);                                             \
      STAGE_V((kt) + 2, ((kt) + 2) % 3);                                       \
    }                                                                          \
    if ((kt) + 1 < 32) DO_QK(SNXT, ((kt) + 1) & 1);                            \
    DO_SMPV(SCUR, (kt) % 3);                                                   \
    __syncthreads();                                                           \
  }

#pragma unroll 2
  for (int kt2 = 0; kt2 < 32; kt2 += 2) {
    ITER(kt2, scA, scB);
    ITER(kt2 + 1, scB, scA);
  }
#undef ITER
#undef DO_SMPV
#undef DO_QK
#undef STAGE_K
#undef STAGE_V

#pragma unroll
  for (int r = 0; r < 4; ++r) {
    float inv = 1.0f / o5[r];
    size_t row = (size_t)(b * 2048 + q0 + w * 16 + g4 * 4 + r);
#pragma unroll
    for (int fh = 0; fh < 4; ++fh)
      ob[row * 768 + h * 64 + fh * 16 + c15] = __float2bfloat16(o[fh][r] * inv);
  }
}

// ----------------------------------------------------------------
extern "C" void kernel_launch(void* const* d_in, const int* in_sizes, int n_in,
                              void* d_out, int out_size, void* d_ws, size_t ws_size,
                              hipStream_t stream) {
  const float* x      = (const float*)d_in[0];
  const float* pcw    = (const float*)d_in[1];
  const float* pcb    = (const float*)d_in[2];
  const float* ln0_g  = (const float*)d_in[3];
  const float* ln0_b  = (const float*)d_in[4];
  const float* Wq     = (const float*)d_in[5];
  const float* bq     = (const float*)d_in[6];
  const float* Wk     = (const float*)d_in[7];
  const float* bk     = (const float*)d_in[8];
  const float* Wv     = (const float*)d_in[9];
  const float* bv     = (const float*)d_in[10];
  const float* Wo     = (const float*)d_in[11];
  const float* bo     = (const float*)d_in[12];
  const float* ln1_g  = (const float*)d_in[13];
  const float* ln1_b  = (const float*)d_in[14];
  const float* W1     = (const float*)d_in[15];
  const float* b1     = (const float*)d_in[16];
  const float* W2     = (const float*)d_in[17];
  const float* b2     = (const float*)d_in[18];
  const float* ln2_g  = (const float*)d_in[19];
  const float* ln2_b  = (const float*)d_in[20];

  const size_t MDB = (size_t)M_TOK * D_ * 4;
  char* W = (char*)d_ws;
  float* tmp  = (float*)(W + MDB);
  char*  big  = W + 2 * MDB;
  bf16*  qkv  = (bf16*)big;
  bf16*  ff   = (bf16*)big;
  bf16*  wT2  = (bf16*)big;
  bf16*  tmp_bf = (bf16*)W;
  char* p = W + 2 * MDB + 25165824;
  bf16* h_bf  = (bf16*)p; p += (size_t)M_TOK * D_ * 2;
  bf16* obuf  = (bf16*)p; p += (size_t)M_TOK * D_ * 2;
  bf16* vT    = (bf16*)p; p += (size_t)M_TOK * D_ * 2;
  bf16* wqkvb = (bf16*)p; p += (size_t)2304 * 768 * 2;
  bf16* wob   = (bf16*)p; p += (size_t)768 * 768 * 2;
  bf16* w1b   = (bf16*)p; p += (size_t)3072 * 768 * 2;
  bf16* w2b   = (bf16*)p; p += (size_t)768 * 3072 * 2;
  float* bqkv = (float*)p;

  convw_kernel<<<24576, 256, 0, stream>>>(pcw, wT2);
  conv_mfma<<<512, 256, 0, stream>>>(x, wT2, pcb, tmp);
  ln_kernel<<<M_TOK / 4, 256, 0, stream>>>(tmp, ln0_g, ln0_b, h_bf);

  for (int l = 0; l < NL_; ++l) {
    prep_weights<<<6921, 256, 0, stream>>>(Wq, Wk, Wv, Wo, W1, W2, bq, bk, bv,
                                           wqkvb, wob, w1b, w2b, bqkv, l);

    gemm_bf16<128, 128, 64, 0, 1, 1><<<dim3(18, 32), 256, 0, stream>>>(h_bf, wqkvb, bqkv, qkv, 2304, 768, vT);
    attn_mfma<<<dim3(32, 12, 2), 256, 0, stream>>>(qkv, vT, obuf);
    gemm_bf16<64, 64, 128, 0, 1><<<dim3(12, 64), 256, 0, stream>>>(obuf, wob, bo + (size_t)l * D_, tmp_bf, 768, 768);
    ln_bf<0><<<M_TOK / 4, 256, 0, stream>>>(tmp_bf, h_bf, ln1_g + (size_t)l * D_, ln1_b + (size_t)l * D_, h_bf, nullptr);
    gemm_bf16<128, 128, 64, 1, 1><<<dim3(24, 32), 256, 0, stream>>>(h_bf, w1b, b1 + (size_t)l * F_, ff, 3072, 768);
    gemm_bf16<64, 64, 128, 0, 1><<<dim3(12, 64), 256, 0, stream>>>(ff, w2b, b2 + (size_t)l * D_, tmp_bf, 768, 3072);
    if (l == NL_ - 1)
      ln_bf<1><<<M_TOK / 4, 256, 0, stream>>>(tmp_bf, h_bf, ln2_g + (size_t)l * D_, ln2_b + (size_t)l * D_, h_bf, (float*)d_out);
    else
      ln_bf<0><<<M_TOK / 4, 256, 0, stream>>>(tmp_bf, h_bf, ln2_g + (size_t)l * D_, ln2_b + (size_t)l * D_, h_bf, nullptr);
  }
}